// Round 2
// baseline (19796.544 us; speedup 1.0000x reference)
//
#include <hip/hip_runtime.h>
#include <math.h>

#define B_    32
#define P_    4096
#define N_    1024
#define POS_  10
#define PP    (P_ + 2)     // padded phoneme rows (guard top/bottom)
#define NP    (N_ + 2)     // padded note rows
#define GB    8            // batches per phase-A chunk
#define NCHK  (B_ / GB)    // 4 phase-A chunks
#define TCH   256          // LSTM time chunk
#define NTCH  (N_ / TCH)   // 4 time chunks
#define CIN1P 272          // conv1 padded input channels (266 real)

typedef unsigned short u16;

// ---------------- helpers ----------------
__device__ __forceinline__ float sigmoidf_(float x) { return 1.f / (1.f + __expf(-x)); }
__device__ __forceinline__ float tanhf_(float x) {
  float t = fminf(fmaxf(x, -30.f), 30.f);
  float e = __expf(2.f * t);
  return (e - 1.f) / (e + 1.f);
}
__device__ __forceinline__ float bf2f(u16 u) { return __uint_as_float(((unsigned)u) << 16); }
__device__ __forceinline__ u16 f2bf(float f) {
  unsigned u = __float_as_uint(f);
  unsigned r = u + 0x7FFFu + ((u >> 16) & 1u);
  return (u16)(r >> 16);
}
__device__ __forceinline__ float ldA(const float* p) { return *p; }
__device__ __forceinline__ float ldA(const u16* p) { return bf2f(*p); }

// ---------------- diagnostics ----------------
__global__ void fill_sentinel_kernel(float* out, int n, float v) {
  int i = blockIdx.x * 256 + threadIdx.x;
  if (i < n) out[i] = v;
}

// ---------------- zero guards ----------------
__global__ void zero_chunk_guards_kernel(float* X0c, float* X1c) {
  int cb = blockIdx.x, t = threadIdx.x;
  for (int c = t; c < CIN1P; c += 256) {
    X0c[((long)cb * PP + 0) * CIN1P + c] = 0.f;
    X0c[((long)cb * PP + PP - 1) * CIN1P + c] = 0.f;
  }
  if (t < 256) {
    X1c[((long)cb * PP + 0) * 256 + t] = 0.f;
    X1c[((long)cb * PP + PP - 1) * 256 + t] = 0.f;
  }
}
__global__ void zero_y1p_guards_kernel(u16* Y1p) {
  int b = blockIdx.x, t = threadIdx.x;
  for (int c = t; c < 512; c += 256) {
    Y1p[((long)b * NP + 0) * 512 + c] = 0;
    Y1p[((long)b * NP + NP - 1) * 512 + c] = 0;
  }
}
__global__ void zero_c3p_guards_kernel(float* C3p) {
  int b = blockIdx.x, t = threadIdx.x;
  if (t < 256) {
    C3p[((long)b * NP + 0) * 256 + t] = 0.f;
    C3p[((long)b * NP + NP - 1) * 256 + t] = 0.f;
  }
}

// ---------------- embedding (chunked) ----------------
__global__ void embed_chunk_kernel(const int* __restrict__ seq, const int* __restrict__ order,
                                   const float* __restrict__ emb, const float* __restrict__ pos_emb,
                                   float* __restrict__ X0c, int b0) {
  long i = (long)blockIdx.x * 256 + threadIdx.x;
  const long total = (long)GB * P_ * CIN1P;
  if (i >= total) return;
  int c = (int)(i % CIN1P);
  long bp = i / CIN1P;
  int p = (int)(bp % P_);
  int cb = (int)(bp / P_);
  int b = b0 + cb;
  float v = 0.f;
  if (c < 256)      v = emb[(long)seq[(long)b * P_ + p] * 256 + c];
  else if (c < 266) v = pos_emb[(long)order[(long)b * P_ + p] * POS_ + (c - 256)];
  X0c[((long)cb * PP + p + 1) * CIN1P + c] = v;
}

// ---------------- weight repacks ----------------
// conv w[co][ci][r] -> dst[k = r*CinPad + ci][co], zero where ci >= CinReal
__global__ void repack_conv_w_kernel(const float* __restrict__ w, float* __restrict__ dst,
                                     int CinReal, int CinPad, int Cout) {
  long i = (long)blockIdx.x * 256 + threadIdx.x;
  long total = 3L * CinPad * Cout;
  if (i >= total) return;
  int k = (int)(i / Cout), co = (int)(i - (long)k * Cout);
  int rr = k / CinPad, ci = k - rr * CinPad;
  dst[i] = (ci < CinReal) ? w[((long)co * CinReal + ci) * 3 + rr] : 0.f;
}
// dense w[co(1024)][k(CinReal)] -> dst[k][co], zero k >= CinReal
__global__ void repack_dense_w_kernel(const float* __restrict__ w, float* __restrict__ dst,
                                      int CinReal, int Kpad) {
  long i = (long)blockIdx.x * 256 + threadIdx.x;
  if (i >= (long)Kpad * 1024) return;
  int k = (int)(i >> 10), co = (int)(i & 1023);
  dst[i] = (k < CinReal) ? w[(long)co * CinReal + k] : 0.f;
}
// whh[d][gate*256+u][k] -> float4 quad dst[d][k][u] = (wi,wf,wg,wo)
__global__ void repack_whh_q_kernel(const float* __restrict__ whh, float4* __restrict__ dst) {
  long i = (long)blockIdx.x * 256 + threadIdx.x;
  if (i >= 2L * 256 * 256) return;
  int u = (int)(i & 255), k = (int)((i >> 8) & 255), d = (int)(i >> 16);
  const float* wd = whh + (long)d * 1024 * 256;
  float4 o;
  o.x = wd[(long)(0 * 256 + u) * 256 + k];
  o.y = wd[(long)(1 * 256 + u) * 256 + k];
  o.z = wd[(long)(2 * 256 + u) * 256 + k];
  o.w = wd[(long)(3 * 256 + u) * 256 + k];
  dst[i] = o;
}
__global__ void bias_sum_kernel(const float* __restrict__ a, const float* __restrict__ b,
                                float* __restrict__ dst, int n) {
  int i = blockIdx.x * 256 + threadIdx.x;
  if (i < n) dst[i] = a[i] + b[i];
}
// cnn_w2 [1][256][3] -> dst[k = r*256 + ci]
__global__ void repack_conv4_w_kernel(const float* __restrict__ w, float* __restrict__ dst) {
  int i = blockIdx.x * 256 + threadIdx.x;
  if (i < 768) { int r = i >> 8, ci = i & 255; dst[i] = w[ci * 3 + r]; }
}

// ---------------- rows-GEMM: C = A_rows @ Bm[Kpad x N] + bias ----------------
template <typename AT>
__global__ __launch_bounds__(256) void gemm_rows_kernel(
    const AT* __restrict__ A, const float* __restrict__ Bm,
    const float* __restrict__ bias, float* __restrict__ C,
    int N, int Kpad, int Mb,
    long aBatchStride, int aRowStride,
    long cBatchStride, int cRowStride,
    int relu) {
  __shared__ float As[16][64];   // [k][row]
  __shared__ float Bs[16][64];   // [k][col]
  int tid = threadIdx.x;
  int row0 = blockIdx.x * 64;
  int col0 = blockIdx.y * 64;
  int tx = tid & 15, ty = tid >> 4;
  int ar = tid >> 2, akq = (tid & 3) * 4;
  int grow = row0 + ar;
  int b_ = grow / Mb, m_ = grow - b_ * Mb;
  const AT* arow = A + (long)b_ * aBatchStride + (long)m_ * aRowStride;
  int kb = tid >> 4, nq = (tid & 15) * 4;
  const float* bptr = Bm + (long)kb * N + col0 + nq;

  float acc[4][4];
#pragma unroll
  for (int i = 0; i < 4; i++)
#pragma unroll
    for (int j = 0; j < 4; j++) acc[i][j] = 0.f;

  for (int k0 = 0; k0 < Kpad; k0 += 16) {
    float a0 = ldA(arow + k0 + akq + 0);
    float a1 = ldA(arow + k0 + akq + 1);
    float a2 = ldA(arow + k0 + akq + 2);
    float a3 = ldA(arow + k0 + akq + 3);
    float4 b4 = *(const float4*)(bptr + (long)k0 * N);
    __syncthreads();
    As[akq + 0][ar] = a0;
    As[akq + 1][ar] = a1;
    As[akq + 2][ar] = a2;
    As[akq + 3][ar] = a3;
    *(float4*)&Bs[kb][nq] = b4;
    __syncthreads();
#pragma unroll
    for (int kk = 0; kk < 16; ++kk) {
      float4 av = *(const float4*)&As[kk][ty * 4];
      float4 bv = *(const float4*)&Bs[kk][tx * 4];
      acc[0][0] += av.x * bv.x; acc[0][1] += av.x * bv.y; acc[0][2] += av.x * bv.z; acc[0][3] += av.x * bv.w;
      acc[1][0] += av.y * bv.x; acc[1][1] += av.y * bv.y; acc[1][2] += av.y * bv.z; acc[1][3] += av.y * bv.w;
      acc[2][0] += av.z * bv.x; acc[2][1] += av.z * bv.y; acc[2][2] += av.z * bv.z; acc[2][3] += av.z * bv.w;
      acc[3][0] += av.w * bv.x; acc[3][1] += av.w * bv.y; acc[3][2] += av.w * bv.z; acc[3][3] += av.w * bv.w;
    }
  }
  float4 bb = *(const float4*)&bias[col0 + tx * 4];
#pragma unroll
  for (int i = 0; i < 4; i++) {
    int gr = row0 + ty * 4 + i;
    int b2 = gr / Mb, m2 = gr - b2 * Mb;
    float4 o;
    o.x = acc[i][0] + bb.x; o.y = acc[i][1] + bb.y; o.z = acc[i][2] + bb.z; o.w = acc[i][3] + bb.w;
    if (relu) { o.x = fmaxf(o.x, 0.f); o.y = fmaxf(o.y, 0.f); o.z = fmaxf(o.z, 0.f); o.w = fmaxf(o.w, 0.f); }
    *(float4*)(C + (long)b2 * cBatchStride + (long)m2 * cRowStride + col0 + tx * 4) = o;
  }
}

// ---------------- note-segment scan (per batch) ----------------
__global__ void seg_scan_kernel(const int* __restrict__ seq,
                                int* __restrict__ nstart, int* __restrict__ nlen) {
  __shared__ int s[P_];
  int b = blockIdx.x;
  for (int i = threadIdx.x; i < P_; i += blockDim.x) s[i] = seq[(long)b * P_ + i];
  for (int n = threadIdx.x; n < N_; n += blockDim.x) { nstart[b * N_ + n] = 0; nlen[b * N_ + n] = 0; }
  __syncthreads();
  if (threadIdx.x == 0) {
    int n = -1; bool prev = false;
    for (int p = 0; p < P_ - 1; p++) {   // last position never included
      bool v = s[p] > 1;
      if (v && !prev) n++;
      if (v && n < N_) { if (!prev) nstart[b * N_ + n] = p; nlen[b * N_ + n]++; }
      prev = v;
    }
  }
}

// ---------------- segment mean + enc (bf16, stride 272) ----------------
__global__ __launch_bounds__(256) void agg_enc_kernel(
    const float* __restrict__ X2c, const int* __restrict__ nstart, const int* __restrict__ nlen,
    const float* __restrict__ dur, u16* __restrict__ enc, int b0) {
  int n = blockIdx.x, gb = blockIdx.y;
  int b = b0 + gb;
  int d = threadIdx.x;
  int len = nlen[b * N_ + n], st = nstart[b * N_ + n];
  float acc = 0.f;
  for (int i = 0; i < len; i++) acc += X2c[((long)gb * PP + st + 1 + i) * CIN1P + d];
  float m = (len > 0) ? acc / (float)len : 0.f;
  long e = ((long)b * N_ + n) * 272;
  enc[e + d] = f2bf(m);
  if (d == 0) {
    float dd = dur[b * N_ + n];
    enc[e + 256] = f2bf(dd);
    enc[e + 257] = f2bf(1.f / (dd + 1.f));
  }
  if (d >= 2 && d < 16) enc[e + 256 + d] = 0;  // zero tail 258..271
}

// ---------------- LSTM recurrence (time-chunked, state carry) ----------------
// Z: [2][32][TCH][1024] fp32 (x-proj + both biases). Wq: [2][256k][256u] float4 gate quads.
__global__ __launch_bounds__(256) void lstm_rec_chunk_kernel(
    const float* __restrict__ Z, const float4* __restrict__ Wq,
    float* __restrict__ state, u16* __restrict__ Y,
    int yRowsPerB, int yPad, int r) {
  int chain = blockIdx.x;
  int d = chain >> 5, b = chain & 31;
  int j = threadIdx.x;
  __shared__ float hs[256];
  const float* Zb = Z + (long)(d * 32 + b) * (TCH * 1024);
  const float4* Wd = Wq + (long)d * 256 * 256;
  float c;
  if (r == 0) { hs[j] = 0.f; c = 0.f; }
  else { hs[j] = state[(chain * 2 + 0) * 256 + j]; c = state[(chain * 2 + 1) * 256 + j]; }
  __syncthreads();
  int t0 = (d == 0) ? r * TCH : (NTCH - 1 - r) * TCH;
  for (int tt = 0; tt < TCH; ++tt) {
    int tc = d ? (TCH - 1 - tt) : tt;
    const float* zr = Zb + (long)tc * 1024;
    float ai = zr[j], af = zr[256 + j], ag = zr[512 + j], ao = zr[768 + j];
    for (int k0 = 0; k0 < 256; k0 += 4) {
      float4 h4 = *(const float4*)&hs[k0];
      const float* hp = (const float*)&h4;
#pragma unroll
      for (int q = 0; q < 4; ++q) {
        float4 w = Wd[(long)(k0 + q) * 256 + j];
        float hh = hp[q];
        ai += w.x * hh; af += w.y * hh; ag += w.z * hh; ao += w.w * hh;
      }
    }
    float ig = sigmoidf_(ai), fg = sigmoidf_(af), gg = tanhf_(ag), og = sigmoidf_(ao);
    c = fg * c + ig * gg;
    float h = og * tanhf_(c);
    __syncthreads();
    hs[j] = h;
    __syncthreads();
    int t_eff = t0 + tc;
    Y[((long)b * yRowsPerB + t_eff + yPad) * 512 + d * 256 + j] = f2bf(h);
  }
  if (r != NTCH - 1) {
    state[(chain * 2 + 0) * 256 + j] = hs[j];
    state[(chain * 2 + 1) * 256 + j] = c;
  }
}

// ---------------- final conv (Cout=1): wave per row ----------------
__global__ __launch_bounds__(256) void conv4_kernel(
    const float* __restrict__ C3p, const float* __restrict__ w,
    const float* __restrict__ b2, float* __restrict__ out) {
  int row = blockIdx.x * 4 + (threadIdx.x >> 6);
  int lane = threadIdx.x & 63;
  int b = row >> 10, t = row & (N_ - 1);
  const float* a = C3p + ((long)b * NP + t) * 256;
  float acc = 0.f;
  for (int k = lane; k < 768; k += 64) acc += a[k] * w[k];
  for (int off = 32; off; off >>= 1) acc += __shfl_down(acc, off, 64);
  if (lane == 0) out[row] = acc + b2[0];
}

// ---------------- host launcher ----------------
extern "C" void kernel_launch(void* const* d_in, const int* in_sizes, int n_in,
                              void* d_out, int out_size, void* d_ws, size_t ws_size,
                              hipStream_t stream) {
  const float* dur     = (const float*)d_in[0];
  const int*   seq     = (const int*)d_in[1];
  const int*   order   = (const int*)d_in[2];
  const float* emb     = (const float*)d_in[3];
  const float* pos_emb = (const float*)d_in[4];
  const float* mix_w1  = (const float*)d_in[5];
  const float* mix_b1  = (const float*)d_in[6];
  const float* mix_w2  = (const float*)d_in[7];
  const float* mix_b2  = (const float*)d_in[8];
  const float* wih0    = (const float*)d_in[9];
  const float* whh0    = (const float*)d_in[10];
  const float* bih0    = (const float*)d_in[11];
  const float* bhh0    = (const float*)d_in[12];
  const float* wih1    = (const float*)d_in[13];
  const float* whh1    = (const float*)d_in[14];
  const float* bih1    = (const float*)d_in[15];
  const float* bhh1    = (const float*)d_in[16];
  const float* cnn_w1  = (const float*)d_in[17];
  const float* cnn_b1  = (const float*)d_in[18];
  const float* cnn_w2  = (const float*)d_in[19];
  const float* cnn_b2  = (const float*)d_in[20];
  float* out = (float*)d_out;
  float* ws = (float*)d_ws;

  // ---- workspace layout (float units, 16-aligned) ----
  const long X0C_E = (long)GB * PP * CIN1P;       // 8,917,248
  const long X1C_E = (long)GB * PP * 256;         // 8,392,704
  const long Z_E   = 2L * B_ * TCH * 1024;        // 16,777,216
  const long C3P_E = (long)B_ * NP * 256;         // 8,404,992
  long region = X0C_E + X1C_E;                    // phase-A chunks; also holds Z and C3p
  if (Z_E > region) region = Z_E;
  if (C3P_E > region) region = C3P_E;

  long off = 0;
  auto alloc = [&](long n) { long ret = off; off += (n + 15) & ~15L; return ret; };
  long o_region = alloc(region);
  long o_enc    = alloc(((long)B_ * N_ * 272 + 1) / 2);   // bf16
  long o_Y0     = alloc(((long)B_ * N_ * 512 + 1) / 2);   // bf16
  long o_Y1p    = alloc(((long)B_ * NP * 512 + 1) / 2);   // bf16
  long o_W1r    = alloc(3L * CIN1P * 256);
  long o_W2r    = alloc(3L * 256 * 256);
  long o_Wc1r   = alloc(3L * 512 * 256);
  long o_Wc2r   = alloc(768);
  long o_Wih0r  = alloc(2L * 272 * 1024);
  long o_Wih1r  = alloc(2L * 512 * 1024);
  long o_Wq0    = alloc(2L * 256 * 256 * 4);
  long o_Wq1    = alloc(2L * 256 * 256 * 4);
  long o_bs0    = alloc(2048);
  long o_bs1    = alloc(2048);
  long o_state  = alloc(64L * 2 * 256);
  long o_nst    = alloc((long)B_ * N_);
  long o_nln    = alloc((long)B_ * N_);

  if ((size_t)(off * 4) > ws_size) {
    // encode ws budget: absmax ~= 1000 + ws_MB (ref is all-negative, small tail)
    float v = -(1000.0f + (float)(ws_size >> 20));
    fill_sentinel_kernel<<<(out_size + 255) / 256, 256, 0, stream>>>(out, out_size, v);
    return;
  }

  float* X0c  = ws + o_region;
  float* X1c  = ws + o_region + X0C_E;
  float* Z    = ws + o_region;              // alias (after phase A)
  float* C3p  = ws + o_region;              // alias (after recs)
  u16*   enc  = (u16*)(ws + o_enc);
  u16*   Y0   = (u16*)(ws + o_Y0);
  u16*   Y1p  = (u16*)(ws + o_Y1p);
  float* W1r  = ws + o_W1r;
  float* W2r  = ws + o_W2r;
  float* Wc1r = ws + o_Wc1r;
  float* Wc2r = ws + o_Wc2r;
  float* Wih0r = ws + o_Wih0r;
  float* Wih1r = ws + o_Wih1r;
  float4* Wq0 = (float4*)(ws + o_Wq0);
  float4* Wq1 = (float4*)(ws + o_Wq1);
  float* bs0  = ws + o_bs0;
  float* bs1  = ws + o_bs1;
  float* state = ws + o_state;
  int* nstart = (int*)(ws + o_nst);
  int* nlen   = (int*)(ws + o_nln);

  // ---- repacks / setup ----
  zero_chunk_guards_kernel<<<GB, 256, 0, stream>>>(X0c, X1c);
  zero_y1p_guards_kernel<<<B_, 256, 0, stream>>>(Y1p);
  repack_conv_w_kernel<<<(int)((3L * CIN1P * 256 + 255) / 256), 256, 0, stream>>>(mix_w1, W1r, 266, CIN1P, 256);
  repack_conv_w_kernel<<<(int)((3L * 256 * 256 + 255) / 256), 256, 0, stream>>>(mix_w2, W2r, 256, 256, 256);
  repack_conv_w_kernel<<<(int)((3L * 512 * 256 + 255) / 256), 256, 0, stream>>>(cnn_w1, Wc1r, 512, 512, 256);
  repack_conv4_w_kernel<<<3, 256, 0, stream>>>(cnn_w2, Wc2r);
  for (int d = 0; d < 2; d++) {
    repack_dense_w_kernel<<<(272 * 1024 + 255) / 256, 256, 0, stream>>>(
        wih0 + (long)d * 1024 * 258, Wih0r + (long)d * 272 * 1024, 258, 272);
    repack_dense_w_kernel<<<(512 * 1024 + 255) / 256, 256, 0, stream>>>(
        wih1 + (long)d * 1024 * 512, Wih1r + (long)d * 512 * 1024, 512, 512);
  }
  repack_whh_q_kernel<<<512, 256, 0, stream>>>(whh0, Wq0);
  repack_whh_q_kernel<<<512, 256, 0, stream>>>(whh1, Wq1);
  bias_sum_kernel<<<8, 256, 0, stream>>>(bih0, bhh0, bs0, 2048);
  bias_sum_kernel<<<8, 256, 0, stream>>>(bih1, bhh1, bs1, 2048);
  seg_scan_kernel<<<B_, 256, 0, stream>>>(seq, nstart, nlen);

  // ---- phase A: embed -> conv1 -> conv2 -> aggregate (8-batch chunks) ----
  for (int ch = 0; ch < NCHK; ch++) {
    int b0 = ch * GB;
    long total = (long)GB * P_ * CIN1P;
    embed_chunk_kernel<<<(int)((total + 255) / 256), 256, 0, stream>>>(seq, order, emb, pos_emb, X0c, b0);
    // conv1 (relu): rows GB*P, K=816 exact
    gemm_rows_kernel<float><<<dim3(GB * P_ / 64, 4), 256, 0, stream>>>(
        X0c, W1r, mix_b1, X1c + 256,
        256, 3 * CIN1P, P_, (long)PP * CIN1P, CIN1P, (long)PP * 256, 256, 1);
    // conv2: rows GB*P, K=768 exact -> X2c (= X0c region, stride 272)
    gemm_rows_kernel<float><<<dim3(GB * P_ / 64, 4), 256, 0, stream>>>(
        X1c, W2r, mix_b2, X0c + CIN1P,
        256, 768, P_, (long)PP * 256, 256, (long)PP * CIN1P, CIN1P, 0);
    agg_enc_kernel<<<dim3(N_, GB), 256, 0, stream>>>(X0c, nstart, nlen, dur, enc, b0);
  }

  // ---- LSTM layers (time-chunked Z, fused GEMM + sequential rec) ----
  const long ZD = (long)B_ * TCH * 1024;   // per-dir Z stride
  for (int layer = 0; layer < 2; layer++) {
    const u16*  Xl   = (layer == 0) ? enc : Y0;
    int         xstr = (layer == 0) ? 272 : 512;
    int         Kp   = (layer == 0) ? 272 : 512;
    const float* Wih = (layer == 0) ? Wih0r : Wih1r;
    long        WihD = (layer == 0) ? (long)272 * 1024 : (long)512 * 1024;
    const float* bsl = (layer == 0) ? bs0 : bs1;
    const float4* Wq = (layer == 0) ? Wq0 : Wq1;
    u16*        Yl   = (layer == 0) ? Y0 : Y1p;
    int         yRows = (layer == 0) ? N_ : NP;
    int         yPad  = (layer == 0) ? 0 : 1;
    for (int r = 0; r < NTCH; r++) {
      for (int d = 0; d < 2; d++) {
        int t0 = (d == 0) ? r * TCH : (NTCH - 1 - r) * TCH;
        gemm_rows_kernel<u16><<<dim3(B_ * TCH / 64, 16), 256, 0, stream>>>(
            Xl + (long)t0 * xstr, Wih + (long)d * WihD, bsl + d * 1024, Z + d * ZD,
            1024, Kp, TCH, (long)N_ * xstr, xstr, (long)TCH * 1024, 1024, 0);
      }
      lstm_rec_chunk_kernel<<<64, 256, 0, stream>>>(Z, Wq, state, Yl, yRows, yPad, r);
    }
  }

  // ---- head: conv(relu) K=1536 exact, then 1-channel conv ----
  zero_c3p_guards_kernel<<<B_, 256, 0, stream>>>(C3p);
  gemm_rows_kernel<u16><<<dim3(B_ * N_ / 64, 4), 256, 0, stream>>>(
      Y1p, Wc1r, cnn_b1, C3p + 256,
      256, 1536, N_, (long)NP * 512, 512, (long)NP * 256, 256, 1);
  conv4_kernel<<<B_ * N_ / 4, 256, 0, stream>>>(C3p, Wc2r, cnn_b2, out);
}

// Round 3
// 7647.546 us; speedup vs baseline: 2.5886x; 2.5886x over previous
//
#include <hip/hip_runtime.h>
#include <math.h>

#define B_    32
#define P_    4096
#define N_    1024
#define POS_  10
#define PP    (P_ + 2)     // padded phoneme rows (guard top/bottom)
#define NP    (N_ + 2)     // padded note rows
#define GB    8            // batches per phase-A chunk
#define NCHK  (B_ / GB)    // 4 phase-A chunks
#define TCH   256          // LSTM time chunk
#define NTCH  (N_ / TCH)   // 4 time chunks
#define CIN1P 272          // conv1 padded input channels (266 real)

typedef unsigned short u16;
typedef _Float16 h2_t __attribute__((ext_vector_type(2)));

// ---------------- helpers ----------------
__device__ __forceinline__ float sigmoidf_(float x) { return 1.f / (1.f + __expf(-x)); }
__device__ __forceinline__ float tanhf_(float x) {
  float t = fminf(fmaxf(x, -30.f), 30.f);
  float e = __expf(2.f * t);
  return (e - 1.f) / (e + 1.f);
}
__device__ __forceinline__ float bf2f(u16 u) { return __uint_as_float(((unsigned)u) << 16); }
__device__ __forceinline__ u16 f2bf(float f) {
  unsigned u = __float_as_uint(f);
  unsigned r = u + 0x7FFFu + ((u >> 16) & 1u);
  return (u16)(r >> 16);
}
__device__ __forceinline__ float ldA(const float* p) { return *p; }
__device__ __forceinline__ float ldA(const u16* p) { return bf2f(*p); }
__device__ __forceinline__ u16 f2h_bits(float x) {
  _Float16 hh = (_Float16)x; u16 u; __builtin_memcpy(&u, &hh, 2); return u;
}
__device__ __forceinline__ unsigned pack2h(float lo, float hi) {
  return (unsigned)f2h_bits(lo) | ((unsigned)f2h_bits(hi) << 16);
}
__device__ __forceinline__ float dot2(unsigned w, unsigned h, float acc) {
  return __builtin_amdgcn_fdot2(__builtin_bit_cast(h2_t, w), __builtin_bit_cast(h2_t, h), acc, false);
}
#define DOT4(acc, wq, hq) \
  acc = dot2((wq).x, (hq).x, acc); acc = dot2((wq).y, (hq).y, acc); \
  acc = dot2((wq).z, (hq).z, acc); acc = dot2((wq).w, (hq).w, acc);

// ---------------- diagnostics ----------------
__global__ void fill_sentinel_kernel(float* out, int n, float v) {
  int i = blockIdx.x * 256 + threadIdx.x;
  if (i < n) out[i] = v;
}

// ---------------- zero guards ----------------
__global__ void zero_chunk_guards_kernel(float* X0c, float* X1c) {
  int cb = blockIdx.x, t = threadIdx.x;
  for (int c = t; c < CIN1P; c += 256) {
    X0c[((long)cb * PP + 0) * CIN1P + c] = 0.f;
    X0c[((long)cb * PP + PP - 1) * CIN1P + c] = 0.f;
  }
  if (t < 256) {
    X1c[((long)cb * PP + 0) * 256 + t] = 0.f;
    X1c[((long)cb * PP + PP - 1) * 256 + t] = 0.f;
  }
}
__global__ void zero_y1p_guards_kernel(u16* Y1p) {
  int b = blockIdx.x, t = threadIdx.x;
  for (int c = t; c < 512; c += 256) {
    Y1p[((long)b * NP + 0) * 512 + c] = 0;
    Y1p[((long)b * NP + NP - 1) * 512 + c] = 0;
  }
}
__global__ void zero_c3p_guards_kernel(float* C3p) {
  int b = blockIdx.x, t = threadIdx.x;
  if (t < 256) {
    C3p[((long)b * NP + 0) * 256 + t] = 0.f;
    C3p[((long)b * NP + NP - 1) * 256 + t] = 0.f;
  }
}

// ---------------- embedding (chunked) ----------------
__global__ void embed_chunk_kernel(const int* __restrict__ seq, const int* __restrict__ order,
                                   const float* __restrict__ emb, const float* __restrict__ pos_emb,
                                   float* __restrict__ X0c, int b0) {
  long i = (long)blockIdx.x * 256 + threadIdx.x;
  const long total = (long)GB * P_ * CIN1P;
  if (i >= total) return;
  int c = (int)(i % CIN1P);
  long bp = i / CIN1P;
  int p = (int)(bp % P_);
  int cb = (int)(bp / P_);
  int b = b0 + cb;
  float v = 0.f;
  if (c < 256)      v = emb[(long)seq[(long)b * P_ + p] * 256 + c];
  else if (c < 266) v = pos_emb[(long)order[(long)b * P_ + p] * POS_ + (c - 256)];
  X0c[((long)cb * PP + p + 1) * CIN1P + c] = v;
}

// ---------------- weight repacks ----------------
__global__ void repack_conv_w_kernel(const float* __restrict__ w, float* __restrict__ dst,
                                     int CinReal, int CinPad, int Cout) {
  long i = (long)blockIdx.x * 256 + threadIdx.x;
  long total = 3L * CinPad * Cout;
  if (i >= total) return;
  int k = (int)(i / Cout), co = (int)(i - (long)k * Cout);
  int rr = k / CinPad, ci = k - rr * CinPad;
  dst[i] = (ci < CinReal) ? w[((long)co * CinReal + ci) * 3 + rr] : 0.f;
}
__global__ void repack_dense_w_kernel(const float* __restrict__ w, float* __restrict__ dst,
                                      int CinReal, int Kpad) {
  long i = (long)blockIdx.x * 256 + threadIdx.x;
  if (i >= (long)Kpad * 1024) return;
  int k = (int)(i >> 10), co = (int)(i & 1023);
  dst[i] = (k < CinReal) ? w[(long)co * CinReal + k] : 0.f;
}
// Whh k<192 slice -> register-resident quads: Wv[((d*2+rb)*24+kq)*512 + j]
// row(j,rb): R = (j&3)*256 + (j>>2) + rb*128; quad q covers k = kq*8+2q, +1
__global__ void repack_whh_reg_kernel(const float* __restrict__ whh, uint4* __restrict__ Wv) {
  long i = (long)blockIdx.x * 256 + threadIdx.x;
  if (i >= 49152) return;
  int j = (int)(i & 511);
  int t = (int)(i >> 9);
  int kq = t % 24, rb = (t / 24) & 1, d = t / 48;
  int R = (j & 3) * 256 + (j >> 2) + rb * 128;
  const float* wr = whh + ((long)d * 1024 + R) * 256;
  uint4 o; unsigned* op = (unsigned*)&o;
#pragma unroll
  for (int q = 0; q < 4; q++) {
    int k = kq * 8 + 2 * q;
    op[q] = pack2h(wr[k], wr[k + 1]);
  }
  Wv[i] = o;
}
// Whh k in [192,256) -> LDS-resident, XOR-swizzled: Ws[d*8192 + jrow*8 + iphys]
// iphys = ilog ^ (jrow&7); quad ilog covers k = 192 + ilog*8 + 2q
__global__ void repack_whh_lds_kernel(const float* __restrict__ whh, uint4* __restrict__ Ws) {
  long i = (long)blockIdx.x * 256 + threadIdx.x;
  if (i >= 16384) return;
  int d = (int)(i >> 13);
  int a = (int)(i & 8191);
  int jrow = a >> 3, iphys = a & 7;
  int ilog = iphys ^ (jrow & 7);
  int R = (jrow & 3) * 256 + (jrow >> 2);
  const float* wr = whh + ((long)d * 1024 + R) * 256;
  uint4 o; unsigned* op = (unsigned*)&o;
#pragma unroll
  for (int q = 0; q < 4; q++) {
    int k = 192 + ilog * 8 + 2 * q;
    op[q] = pack2h(wr[k], wr[k + 1]);
  }
  Ws[i] = o;
}
__global__ void bias_sum_kernel(const float* __restrict__ a, const float* __restrict__ b,
                                float* __restrict__ dst, int n) {
  int i = blockIdx.x * 256 + threadIdx.x;
  if (i < n) dst[i] = a[i] + b[i];
}
__global__ void repack_conv4_w_kernel(const float* __restrict__ w, float* __restrict__ dst) {
  int i = blockIdx.x * 256 + threadIdx.x;
  if (i < 768) { int r = i >> 8, ci = i & 255; dst[i] = w[ci * 3 + r]; }
}

// ---------------- rows-GEMM: C = A_rows @ Bm[Kpad x N] + bias ----------------
template <typename AT>
__global__ __launch_bounds__(256) void gemm_rows_kernel(
    const AT* __restrict__ A, const float* __restrict__ Bm,
    const float* __restrict__ bias, float* __restrict__ C,
    int N, int Kpad, int Mb,
    long aBatchStride, int aRowStride,
    long cBatchStride, int cRowStride,
    int relu) {
  __shared__ float As[16][64];   // [k][row]
  __shared__ float Bs[16][64];   // [k][col]
  int tid = threadIdx.x;
  int row0 = blockIdx.x * 64;
  int col0 = blockIdx.y * 64;
  int tx = tid & 15, ty = tid >> 4;
  int ar = tid >> 2, akq = (tid & 3) * 4;
  int grow = row0 + ar;
  int b_ = grow / Mb, m_ = grow - b_ * Mb;
  const AT* arow = A + (long)b_ * aBatchStride + (long)m_ * aRowStride;
  int kb = tid >> 4, nq = (tid & 15) * 4;
  const float* bptr = Bm + (long)kb * N + col0 + nq;

  float acc[4][4];
#pragma unroll
  for (int i = 0; i < 4; i++)
#pragma unroll
    for (int j = 0; j < 4; j++) acc[i][j] = 0.f;

  for (int k0 = 0; k0 < Kpad; k0 += 16) {
    float a0 = ldA(arow + k0 + akq + 0);
    float a1 = ldA(arow + k0 + akq + 1);
    float a2 = ldA(arow + k0 + akq + 2);
    float a3 = ldA(arow + k0 + akq + 3);
    float4 b4 = *(const float4*)(bptr + (long)k0 * N);
    __syncthreads();
    As[akq + 0][ar] = a0;
    As[akq + 1][ar] = a1;
    As[akq + 2][ar] = a2;
    As[akq + 3][ar] = a3;
    *(float4*)&Bs[kb][nq] = b4;
    __syncthreads();
#pragma unroll
    for (int kk = 0; kk < 16; ++kk) {
      float4 av = *(const float4*)&As[kk][ty * 4];
      float4 bv = *(const float4*)&Bs[kk][tx * 4];
      acc[0][0] += av.x * bv.x; acc[0][1] += av.x * bv.y; acc[0][2] += av.x * bv.z; acc[0][3] += av.x * bv.w;
      acc[1][0] += av.y * bv.x; acc[1][1] += av.y * bv.y; acc[1][2] += av.y * bv.z; acc[1][3] += av.y * bv.w;
      acc[2][0] += av.z * bv.x; acc[2][1] += av.z * bv.y; acc[2][2] += av.z * bv.z; acc[2][3] += av.z * bv.w;
      acc[3][0] += av.w * bv.x; acc[3][1] += av.w * bv.y; acc[3][2] += av.w * bv.z; acc[3][3] += av.w * bv.w;
    }
  }
  float4 bb = *(const float4*)&bias[col0 + tx * 4];
#pragma unroll
  for (int i = 0; i < 4; i++) {
    int gr = row0 + ty * 4 + i;
    int b2 = gr / Mb, m2 = gr - b2 * Mb;
    float4 o;
    o.x = acc[i][0] + bb.x; o.y = acc[i][1] + bb.y; o.z = acc[i][2] + bb.z; o.w = acc[i][3] + bb.w;
    if (relu) { o.x = fmaxf(o.x, 0.f); o.y = fmaxf(o.y, 0.f); o.z = fmaxf(o.z, 0.f); o.w = fmaxf(o.w, 0.f); }
    *(float4*)(C + (long)b2 * cBatchStride + (long)m2 * cRowStride + col0 + tx * 4) = o;
  }
}

// ---------------- note-segment scan (per batch) ----------------
__global__ void seg_scan_kernel(const int* __restrict__ seq,
                                int* __restrict__ nstart, int* __restrict__ nlen) {
  __shared__ int s[P_];
  int b = blockIdx.x;
  for (int i = threadIdx.x; i < P_; i += blockDim.x) s[i] = seq[(long)b * P_ + i];
  for (int n = threadIdx.x; n < N_; n += blockDim.x) { nstart[b * N_ + n] = 0; nlen[b * N_ + n] = 0; }
  __syncthreads();
  if (threadIdx.x == 0) {
    int n = -1; bool prev = false;
    for (int p = 0; p < P_ - 1; p++) {   // last position never included
      bool v = s[p] > 1;
      if (v && !prev) n++;
      if (v && n < N_) { if (!prev) nstart[b * N_ + n] = p; nlen[b * N_ + n]++; }
      prev = v;
    }
  }
}

// ---------------- segment mean + enc (bf16, stride 272) ----------------
__global__ __launch_bounds__(256) void agg_enc_kernel(
    const float* __restrict__ X2c, const int* __restrict__ nstart, const int* __restrict__ nlen,
    const float* __restrict__ dur, u16* __restrict__ enc, int b0) {
  int n = blockIdx.x, gb = blockIdx.y;
  int b = b0 + gb;
  int d = threadIdx.x;
  int len = nlen[b * N_ + n], st = nstart[b * N_ + n];
  float acc = 0.f;
  for (int i = 0; i < len; i++) acc += X2c[((long)gb * PP + st + 1 + i) * CIN1P + d];
  float m = (len > 0) ? acc / (float)len : 0.f;
  long e = ((long)b * N_ + n) * 272;
  enc[e + d] = f2bf(m);
  if (d == 0) {
    float dd = dur[b * N_ + n];
    enc[e + 256] = f2bf(dd);
    enc[e + 257] = f2bf(1.f / (dd + 1.f));
  }
  if (d >= 2 && d < 16) enc[e + 256 + d] = 0;  // zero tail 258..271
}

// ---------------- LSTM recurrence v2: CU-resident fp16 weights ----------------
// 64 WGs (chain = dir*32+b), 512 threads. Thread owns rows j=tid and j=tid+512
// (row j: gate g=j&3, unit u=j>>2; original Whh row R = g*256+u).
// Weights: k<192 in VGPRs (2x24 uint4 of half2), k in [192,256) in 128KB LDS
// (XOR-swizzled). h broadcast per step via LDS b128 reads. dot2 f16 MACs, f32 acc.
#define REC_LDS_BYTES (131072 + 4096 + 1024)
__global__ __launch_bounds__(512, 2) void lstm_rec2_kernel(
    const float* __restrict__ Z,      // [2][32][TCH][1024] fp32 x-proj + biases
    const uint4* __restrict__ Wv,     // [2][2][24][512] fp16 quads (k<192)
    const uint4* __restrict__ Ws,     // [2][8192] fp16 quads, swizzled (k>=192)
    float* __restrict__ state,        // [64][2][256]
    u16* __restrict__ Y, int yRowsPerB, int yPad, int r) {
  extern __shared__ char smem[];
  uint4* WL = (uint4*)smem;                              // 8192 quads
  float* zb = (float*)(smem + 131072);                   // 1024 f32
  u16*   hb = (u16*)(smem + 131072 + 4096);              // 256 fp16
  const uint4* hb4 = (const uint4*)hb;                   // 32 quads

  int chain = blockIdx.x;
  int d = chain >> 5, b = chain & 31;
  int tid = threadIdx.x;
  const float* Zb = Z + (long)(d * 32 + b) * (TCH * 1024);

  // stage LDS weights (linear copy; swizzle pre-baked by repack)
  for (int iq = 0; iq < 16; ++iq) {
    int q = iq * 512 + tid;
    WL[q] = Ws[(long)d * 8192 + q];
  }
  // load register weights
  uint4 wA[24], wB[24];
  const uint4* WvD = Wv + (long)d * 2 * 24 * 512;
#pragma unroll
  for (int kq = 0; kq < 24; kq++) wA[kq] = WvD[(long)kq * 512 + tid];
#pragma unroll
  for (int kq = 0; kq < 24; kq++) wB[kq] = WvD[(long)(24 + kq) * 512 + tid];

  float h_reg = 0.f, c_reg = 0.f;
  if (tid < 256) {
    if (r > 0) {
      h_reg = state[(chain * 2 + 0) * 256 + tid];
      c_reg = state[(chain * 2 + 1) * 256 + tid];
    }
    hb[tid] = f2h_bits(h_reg);
  }
  __syncthreads();

  int colA = (tid & 3) * 256 + (tid >> 2);
  int colB = colA + 128;
  int swz = tid & 7;
  int wlA = tid << 3, wlB = (tid << 3) + 4096;
  int t0 = (d == 0) ? r * TCH : (NTCH - 1 - r) * TCH;

  int tcf = d ? (TCH - 1) : 0;
  float preA = Zb[(long)tcf * 1024 + colA];
  float preB = Zb[(long)tcf * 1024 + colB];

  for (int tt = 0; tt < TCH; ++tt) {
    float accA = preA, accB = preB;
    if (tt + 1 < TCH) {                       // prefetch next step's z
      int tc2 = d ? (TCH - 2 - tt) : (tt + 1);
      preA = Zb[(long)tc2 * 1024 + colA];
      preB = Zb[(long)tc2 * 1024 + colB];
    }
#pragma unroll
    for (int kq = 0; kq < 24; kq++) {
      uint4 hq = hb4[kq];
      DOT4(accA, wA[kq], hq);
      DOT4(accB, wB[kq], hq);
    }
#pragma unroll
    for (int i2 = 0; i2 < 8; i2++) {
      uint4 hq = hb4[24 + i2];
      uint4 qa = WL[wlA + (i2 ^ swz)];
      uint4 qb = WL[wlB + (i2 ^ swz)];
      DOT4(accA, qa, hq);
      DOT4(accB, qb, hq);
    }
    zb[tid] = accA;
    zb[tid + 512] = accB;
    __syncthreads();
    int tcur = d ? (TCH - 1 - tt) : tt;
    if (tid < 256) {
      float4 z4 = *(const float4*)&zb[tid * 4];   // rows u*4+g -> (i,f,g,o)
      float ig = sigmoidf_(z4.x), fg = sigmoidf_(z4.y);
      float gg = tanhf_(z4.z), og = sigmoidf_(z4.w);
      c_reg = fg * c_reg + ig * gg;
      float h = og * tanhf_(c_reg);
      h_reg = h;
      hb[tid] = f2h_bits(h);
      Y[((long)b * yRowsPerB + t0 + tcur + yPad) * 512 + d * 256 + tid] = f2bf(h);
    }
    __syncthreads();
  }
  if (r != NTCH - 1 && tid < 256) {
    state[(chain * 2 + 0) * 256 + tid] = h_reg;
    state[(chain * 2 + 1) * 256 + tid] = c_reg;
  }
}

// ---------------- final conv (Cout=1): wave per row ----------------
__global__ __launch_bounds__(256) void conv4_kernel(
    const float* __restrict__ C3p, const float* __restrict__ w,
    const float* __restrict__ b2, float* __restrict__ out) {
  int row = blockIdx.x * 4 + (threadIdx.x >> 6);
  int lane = threadIdx.x & 63;
  int b = row >> 10, t = row & (N_ - 1);
  const float* a = C3p + ((long)b * NP + t) * 256;
  float acc = 0.f;
  for (int k = lane; k < 768; k += 64) acc += a[k] * w[k];
  for (int off = 32; off; off >>= 1) acc += __shfl_down(acc, off, 64);
  if (lane == 0) out[row] = acc + b2[0];
}

// ---------------- host launcher ----------------
extern "C" void kernel_launch(void* const* d_in, const int* in_sizes, int n_in,
                              void* d_out, int out_size, void* d_ws, size_t ws_size,
                              hipStream_t stream) {
  const float* dur     = (const float*)d_in[0];
  const int*   seq     = (const int*)d_in[1];
  const int*   order   = (const int*)d_in[2];
  const float* emb     = (const float*)d_in[3];
  const float* pos_emb = (const float*)d_in[4];
  const float* mix_w1  = (const float*)d_in[5];
  const float* mix_b1  = (const float*)d_in[6];
  const float* mix_w2  = (const float*)d_in[7];
  const float* mix_b2  = (const float*)d_in[8];
  const float* wih0    = (const float*)d_in[9];
  const float* whh0    = (const float*)d_in[10];
  const float* bih0    = (const float*)d_in[11];
  const float* bhh0    = (const float*)d_in[12];
  const float* wih1    = (const float*)d_in[13];
  const float* whh1    = (const float*)d_in[14];
  const float* bih1    = (const float*)d_in[15];
  const float* bhh1    = (const float*)d_in[16];
  const float* cnn_w1  = (const float*)d_in[17];
  const float* cnn_b1  = (const float*)d_in[18];
  const float* cnn_w2  = (const float*)d_in[19];
  const float* cnn_b2  = (const float*)d_in[20];
  float* out = (float*)d_out;
  float* ws = (float*)d_ws;

  // opt-in to 136 KB dynamic LDS for the rec kernel (config call; capture-safe)
  (void)hipFuncSetAttribute((const void*)lstm_rec2_kernel,
                            hipFuncAttributeMaxDynamicSharedMemorySize, REC_LDS_BYTES);

  // ---- workspace layout (float units, 16-aligned) ----
  const long X0C_E = (long)GB * PP * CIN1P;
  const long X1C_E = (long)GB * PP * 256;
  const long Z_E   = 2L * B_ * TCH * 1024;
  const long C3P_E = (long)B_ * NP * 256;
  long region = X0C_E + X1C_E;
  if (Z_E > region) region = Z_E;
  if (C3P_E > region) region = C3P_E;

  long off = 0;
  auto alloc = [&](long n) { long ret = off; off += (n + 15) & ~15L; return ret; };
  long o_region = alloc(region);
  long o_enc    = alloc(((long)B_ * N_ * 272 + 1) / 2);   // bf16
  long o_Y0     = alloc(((long)B_ * N_ * 512 + 1) / 2);   // bf16
  long o_Y1p    = alloc(((long)B_ * NP * 512 + 1) / 2);   // bf16
  long o_W1r    = alloc(3L * CIN1P * 256);
  long o_W2r    = alloc(3L * 256 * 256);
  long o_Wc1r   = alloc(3L * 512 * 256);
  long o_Wc2r   = alloc(768);
  long o_Wih0r  = alloc(2L * 272 * 1024);
  long o_Wih1r  = alloc(2L * 512 * 1024);
  long o_Wv0    = alloc(49152L * 4);   // uint4 quads (fp16), layer0
  long o_Ws0    = alloc(16384L * 4);
  long o_Wv1    = alloc(49152L * 4);   // layer1
  long o_Ws1    = alloc(16384L * 4);
  long o_bs0    = alloc(2048);
  long o_bs1    = alloc(2048);
  long o_state  = alloc(64L * 2 * 256);
  long o_nst    = alloc((long)B_ * N_);
  long o_nln    = alloc((long)B_ * N_);

  if ((size_t)(off * 4) > ws_size) {
    float v = -(1000.0f + (float)(ws_size >> 20));
    fill_sentinel_kernel<<<(out_size + 255) / 256, 256, 0, stream>>>(out, out_size, v);
    return;
  }

  float* X0c  = ws + o_region;
  float* X1c  = ws + o_region + X0C_E;
  float* Z    = ws + o_region;              // alias (after phase A)
  float* C3p  = ws + o_region;              // alias (after recs)
  u16*   enc  = (u16*)(ws + o_enc);
  u16*   Y0   = (u16*)(ws + o_Y0);
  u16*   Y1p  = (u16*)(ws + o_Y1p);
  float* W1r  = ws + o_W1r;
  float* W2r  = ws + o_W2r;
  float* Wc1r = ws + o_Wc1r;
  float* Wc2r = ws + o_Wc2r;
  float* Wih0r = ws + o_Wih0r;
  float* Wih1r = ws + o_Wih1r;
  uint4* Wv0  = (uint4*)(ws + o_Wv0);
  uint4* Ws0  = (uint4*)(ws + o_Ws0);
  uint4* Wv1  = (uint4*)(ws + o_Wv1);
  uint4* Ws1  = (uint4*)(ws + o_Ws1);
  float* bs0  = ws + o_bs0;
  float* bs1  = ws + o_bs1;
  float* state = ws + o_state;
  int* nstart = (int*)(ws + o_nst);
  int* nlen   = (int*)(ws + o_nln);

  // ---- repacks / setup ----
  zero_chunk_guards_kernel<<<GB, 256, 0, stream>>>(X0c, X1c);
  zero_y1p_guards_kernel<<<B_, 256, 0, stream>>>(Y1p);
  repack_conv_w_kernel<<<(int)((3L * CIN1P * 256 + 255) / 256), 256, 0, stream>>>(mix_w1, W1r, 266, CIN1P, 256);
  repack_conv_w_kernel<<<(int)((3L * 256 * 256 + 255) / 256), 256, 0, stream>>>(mix_w2, W2r, 256, 256, 256);
  repack_conv_w_kernel<<<(int)((3L * 512 * 256 + 255) / 256), 256, 0, stream>>>(cnn_w1, Wc1r, 512, 512, 256);
  repack_conv4_w_kernel<<<3, 256, 0, stream>>>(cnn_w2, Wc2r);
  for (int d = 0; d < 2; d++) {
    repack_dense_w_kernel<<<(272 * 1024 + 255) / 256, 256, 0, stream>>>(
        wih0 + (long)d * 1024 * 258, Wih0r + (long)d * 272 * 1024, 258, 272);
    repack_dense_w_kernel<<<(512 * 1024 + 255) / 256, 256, 0, stream>>>(
        wih1 + (long)d * 1024 * 512, Wih1r + (long)d * 512 * 1024, 512, 512);
  }
  repack_whh_reg_kernel<<<192, 256, 0, stream>>>(whh0, Wv0);
  repack_whh_lds_kernel<<<64, 256, 0, stream>>>(whh0, Ws0);
  repack_whh_reg_kernel<<<192, 256, 0, stream>>>(whh1, Wv1);
  repack_whh_lds_kernel<<<64, 256, 0, stream>>>(whh1, Ws1);
  bias_sum_kernel<<<8, 256, 0, stream>>>(bih0, bhh0, bs0, 2048);
  bias_sum_kernel<<<8, 256, 0, stream>>>(bih1, bhh1, bs1, 2048);
  seg_scan_kernel<<<B_, 256, 0, stream>>>(seq, nstart, nlen);

  // ---- phase A: embed -> conv1 -> conv2 -> aggregate (8-batch chunks) ----
  for (int ch = 0; ch < NCHK; ch++) {
    int b0 = ch * GB;
    long total = (long)GB * P_ * CIN1P;
    embed_chunk_kernel<<<(int)((total + 255) / 256), 256, 0, stream>>>(seq, order, emb, pos_emb, X0c, b0);
    gemm_rows_kernel<float><<<dim3(GB * P_ / 64, 4), 256, 0, stream>>>(
        X0c, W1r, mix_b1, X1c + 256,
        256, 3 * CIN1P, P_, (long)PP * CIN1P, CIN1P, (long)PP * 256, 256, 1);
    gemm_rows_kernel<float><<<dim3(GB * P_ / 64, 4), 256, 0, stream>>>(
        X1c, W2r, mix_b2, X0c + CIN1P,
        256, 768, P_, (long)PP * 256, 256, (long)PP * CIN1P, CIN1P, 0);
    agg_enc_kernel<<<dim3(N_, GB), 256, 0, stream>>>(X0c, nstart, nlen, dur, enc, b0);
  }

  // ---- LSTM layers (time-chunked Z, GEMM + CU-resident rec) ----
  const long ZD = (long)B_ * TCH * 1024;
  for (int layer = 0; layer < 2; layer++) {
    const u16*  Xl   = (layer == 0) ? enc : Y0;
    int         xstr = (layer == 0) ? 272 : 512;
    int         Kp   = (layer == 0) ? 272 : 512;
    const float* Wih = (layer == 0) ? Wih0r : Wih1r;
    long        WihD = (layer == 0) ? (long)272 * 1024 : (long)512 * 1024;
    const float* bsl = (layer == 0) ? bs0 : bs1;
    const uint4* Wv  = (layer == 0) ? Wv0 : Wv1;
    const uint4* Wsp = (layer == 0) ? Ws0 : Ws1;
    u16*        Yl   = (layer == 0) ? Y0 : Y1p;
    int         yRows = (layer == 0) ? N_ : NP;
    int         yPad  = (layer == 0) ? 0 : 1;
    for (int r = 0; r < NTCH; r++) {
      for (int d = 0; d < 2; d++) {
        int t0 = (d == 0) ? r * TCH : (NTCH - 1 - r) * TCH;
        gemm_rows_kernel<u16><<<dim3(B_ * TCH / 64, 16), 256, 0, stream>>>(
            Xl + (long)t0 * xstr, Wih + (long)d * WihD, bsl + d * 1024, Z + d * ZD,
            1024, Kp, TCH, (long)N_ * xstr, xstr, (long)TCH * 1024, 1024, 0);
      }
      lstm_rec2_kernel<<<64, 512, REC_LDS_BYTES, stream>>>(Z, Wv, Wsp, state, Yl, yRows, yPad, r);
    }
  }

  // ---- head: conv(relu) K=1536 exact, then 1-channel conv ----
  zero_c3p_guards_kernel<<<B_, 256, 0, stream>>>(C3p);
  gemm_rows_kernel<u16><<<dim3(B_ * N_ / 64, 4), 256, 0, stream>>>(
      Y1p, Wc1r, cnn_b1, C3p + 256,
      256, 1536, N_, (long)NP * 512, 512, (long)NP * 256, 256, 1);
  conv4_kernel<<<B_ * N_ / 4, 256, 0, stream>>>(C3p, Wc2r, cnn_b2, out);
}

// Round 4
// 6997.107 us; speedup vs baseline: 2.8292x; 1.0930x over previous
//
#include <hip/hip_runtime.h>
#include <math.h>

#define B_    32
#define P_    4096
#define N_    1024
#define POS_  10
#define PP    (P_ + 2)     // padded phoneme rows (guard top/bottom)
#define NP    (N_ + 2)     // padded note rows
#define GB    8            // batches per phase-A chunk
#define NCHK  (B_ / GB)    // 4 phase-A chunks
#define TCH   256          // LSTM time chunk
#define NTCH  (N_ / TCH)   // 4 time chunks
#define CIN1P 272          // conv1 padded input channels (266 real)

typedef unsigned short u16;
typedef _Float16 h2_t __attribute__((ext_vector_type(2)));

// ---------------- helpers ----------------
__device__ __forceinline__ float sigmoidf_(float x) { return 1.f / (1.f + __expf(-x)); }
__device__ __forceinline__ float tanhf_(float x) {
  float t = fminf(fmaxf(x, -30.f), 30.f);
  float e = __expf(2.f * t);
  return (e - 1.f) / (e + 1.f);
}
__device__ __forceinline__ float bf2f(u16 u) { return __uint_as_float(((unsigned)u) << 16); }
__device__ __forceinline__ u16 f2bf(float f) {
  unsigned u = __float_as_uint(f);
  unsigned r = u + 0x7FFFu + ((u >> 16) & 1u);
  return (u16)(r >> 16);
}
__device__ __forceinline__ float ldA(const float* p) { return *p; }
__device__ __forceinline__ float ldA(const u16* p) { return bf2f(*p); }
__device__ __forceinline__ u16 f2h_bits(float x) {
  _Float16 hh = (_Float16)x; u16 u; __builtin_memcpy(&u, &hh, 2); return u;
}
__device__ __forceinline__ unsigned pack2h(float lo, float hi) {
  return (unsigned)f2h_bits(lo) | ((unsigned)f2h_bits(hi) << 16);
}
__device__ __forceinline__ float dot2(unsigned w, unsigned h, float acc) {
  return __builtin_amdgcn_fdot2(__builtin_bit_cast(h2_t, w), __builtin_bit_cast(h2_t, h), acc, false);
}
#define DOT4(acc, wq, hq) \
  acc = dot2((wq).x, (hq).x, acc); acc = dot2((wq).y, (hq).y, acc); \
  acc = dot2((wq).z, (hq).z, acc); acc = dot2((wq).w, (hq).w, acc);

#define REP24(X) X(0)X(1)X(2)X(3)X(4)X(5)X(6)X(7)X(8)X(9)X(10)X(11)X(12)X(13)X(14)X(15)X(16)X(17)X(18)X(19)X(20)X(21)X(22)X(23)
#define REP8(X)  X(0)X(1)X(2)X(3)X(4)X(5)X(6)X(7)

// ---------------- diagnostics ----------------
__global__ void fill_sentinel_kernel(float* out, int n, float v) {
  int i = blockIdx.x * 256 + threadIdx.x;
  if (i < n) out[i] = v;
}

// ---------------- zero guards ----------------
__global__ void zero_chunk_guards_kernel(float* X0c, float* X1c) {
  int cb = blockIdx.x, t = threadIdx.x;
  for (int c = t; c < CIN1P; c += 256) {
    X0c[((long)cb * PP + 0) * CIN1P + c] = 0.f;
    X0c[((long)cb * PP + PP - 1) * CIN1P + c] = 0.f;
  }
  if (t < 256) {
    X1c[((long)cb * PP + 0) * 256 + t] = 0.f;
    X1c[((long)cb * PP + PP - 1) * 256 + t] = 0.f;
  }
}
__global__ void zero_y1p_guards_kernel(u16* Y1p) {
  int b = blockIdx.x, t = threadIdx.x;
  for (int c = t; c < 512; c += 256) {
    Y1p[((long)b * NP + 0) * 512 + c] = 0;
    Y1p[((long)b * NP + NP - 1) * 512 + c] = 0;
  }
}
__global__ void zero_c3p_guards_kernel(float* C3p) {
  int b = blockIdx.x, t = threadIdx.x;
  if (t < 256) {
    C3p[((long)b * NP + 0) * 256 + t] = 0.f;
    C3p[((long)b * NP + NP - 1) * 256 + t] = 0.f;
  }
}

// ---------------- embedding (chunked) ----------------
__global__ void embed_chunk_kernel(const int* __restrict__ seq, const int* __restrict__ order,
                                   const float* __restrict__ emb, const float* __restrict__ pos_emb,
                                   float* __restrict__ X0c, int b0) {
  long i = (long)blockIdx.x * 256 + threadIdx.x;
  const long total = (long)GB * P_ * CIN1P;
  if (i >= total) return;
  int c = (int)(i % CIN1P);
  long bp = i / CIN1P;
  int p = (int)(bp % P_);
  int cb = (int)(bp / P_);
  int b = b0 + cb;
  float v = 0.f;
  if (c < 256)      v = emb[(long)seq[(long)b * P_ + p] * 256 + c];
  else if (c < 266) v = pos_emb[(long)order[(long)b * P_ + p] * POS_ + (c - 256)];
  X0c[((long)cb * PP + p + 1) * CIN1P + c] = v;
}

// ---------------- weight repacks ----------------
__global__ void repack_conv_w_kernel(const float* __restrict__ w, float* __restrict__ dst,
                                     int CinReal, int CinPad, int Cout) {
  long i = (long)blockIdx.x * 256 + threadIdx.x;
  long total = 3L * CinPad * Cout;
  if (i >= total) return;
  int k = (int)(i / Cout), co = (int)(i - (long)k * Cout);
  int rr = k / CinPad, ci = k - rr * CinPad;
  dst[i] = (ci < CinReal) ? w[((long)co * CinReal + ci) * 3 + rr] : 0.f;
}
// dense w[co(1024)][k] -> dst[k][j] with PERMUTED column j: co = R(j) = (j&3)*256 + (j>>2)
__global__ void repack_dense_w_perm_kernel(const float* __restrict__ w, float* __restrict__ dst,
                                           int CinReal, int Kpad) {
  long i = (long)blockIdx.x * 256 + threadIdx.x;
  if (i >= (long)Kpad * 1024) return;
  int k = (int)(i >> 10), j = (int)(i & 1023);
  int co = (j & 3) * 256 + (j >> 2);
  dst[i] = (k < CinReal) ? w[(long)co * CinReal + k] : 0.f;
}
// Whh k<192 slice -> register-resident quads: Wv[((d*2+rb)*24+kq)*512 + j]
// row(j,rb): R = (j&3)*256 + (j>>2) + rb*128; quad q covers k = kq*8+2q, +1
__global__ void repack_whh_reg_kernel(const float* __restrict__ whh, uint4* __restrict__ Wv) {
  long i = (long)blockIdx.x * 256 + threadIdx.x;
  if (i >= 49152) return;
  int j = (int)(i & 511);
  int t = (int)(i >> 9);
  int kq = t % 24, rb = (t / 24) & 1, d = t / 48;
  int R = (j & 3) * 256 + (j >> 2) + rb * 128;
  const float* wr = whh + ((long)d * 1024 + R) * 256;
  uint4 o; unsigned* op = (unsigned*)&o;
#pragma unroll
  for (int q = 0; q < 4; q++) {
    int k = kq * 8 + 2 * q;
    op[q] = pack2h(wr[k], wr[k + 1]);
  }
  Wv[i] = o;
}
// Whh k in [192,256) -> LDS-resident, LINEAR-LANE layout:
// Ws[d*8192 + rb*4096 + i2*512 + j]; R = (j&3)*256 + (j>>2) + rb*128; quad i2 covers k=192+i2*8+2q
__global__ void repack_whh_lds_kernel(const float* __restrict__ whh, uint4* __restrict__ Ws) {
  long i = (long)blockIdx.x * 256 + threadIdx.x;
  if (i >= 16384) return;
  int d = (int)(i >> 13);
  int a = (int)(i & 8191);
  int rb = a >> 12;
  int rem = a & 4095;
  int i2 = rem >> 9, j = rem & 511;
  int R = (j & 3) * 256 + (j >> 2) + rb * 128;
  const float* wr = whh + ((long)d * 1024 + R) * 256;
  uint4 o; unsigned* op = (unsigned*)&o;
#pragma unroll
  for (int q = 0; q < 4; q++) {
    int k = 192 + i2 * 8 + 2 * q;
    op[q] = pack2h(wr[k], wr[k + 1]);
  }
  Ws[i] = o;
}
// permuted bias sum: dst[d*1024 + j] = a[d*1024 + R(j)] + b[d*1024 + R(j)]
__global__ void bias_sum_perm_kernel(const float* __restrict__ a, const float* __restrict__ b,
                                     float* __restrict__ dst) {
  int i = blockIdx.x * 256 + threadIdx.x;
  if (i >= 2048) return;
  int d = i >> 10, j = i & 1023;
  int R = (j & 3) * 256 + (j >> 2);
  dst[i] = a[d * 1024 + R] + b[d * 1024 + R];
}
__global__ void repack_conv4_w_kernel(const float* __restrict__ w, float* __restrict__ dst) {
  int i = blockIdx.x * 256 + threadIdx.x;
  if (i < 768) { int r = i >> 8, ci = i & 255; dst[i] = w[ci * 3 + r]; }
}

// ---------------- rows-GEMM: C = A_rows @ Bm[Kpad x N] + bias ----------------
template <typename AT>
__global__ __launch_bounds__(256) void gemm_rows_kernel(
    const AT* __restrict__ A, const float* __restrict__ Bm,
    const float* __restrict__ bias, float* __restrict__ C,
    int N, int Kpad, int Mb,
    long aBatchStride, int aRowStride,
    long cBatchStride, int cRowStride,
    int relu) {
  __shared__ float As[16][64];   // [k][row]
  __shared__ float Bs[16][64];   // [k][col]
  int tid = threadIdx.x;
  int row0 = blockIdx.x * 64;
  int col0 = blockIdx.y * 64;
  int tx = tid & 15, ty = tid >> 4;
  int ar = tid >> 2, akq = (tid & 3) * 4;
  int grow = row0 + ar;
  int b_ = grow / Mb, m_ = grow - b_ * Mb;
  const AT* arow = A + (long)b_ * aBatchStride + (long)m_ * aRowStride;
  int kb = tid >> 4, nq = (tid & 15) * 4;
  const float* bptr = Bm + (long)kb * N + col0 + nq;

  float acc[4][4];
#pragma unroll
  for (int i = 0; i < 4; i++)
#pragma unroll
    for (int j = 0; j < 4; j++) acc[i][j] = 0.f;

  for (int k0 = 0; k0 < Kpad; k0 += 16) {
    float a0 = ldA(arow + k0 + akq + 0);
    float a1 = ldA(arow + k0 + akq + 1);
    float a2 = ldA(arow + k0 + akq + 2);
    float a3 = ldA(arow + k0 + akq + 3);
    float4 b4 = *(const float4*)(bptr + (long)k0 * N);
    __syncthreads();
    As[akq + 0][ar] = a0;
    As[akq + 1][ar] = a1;
    As[akq + 2][ar] = a2;
    As[akq + 3][ar] = a3;
    *(float4*)&Bs[kb][nq] = b4;
    __syncthreads();
#pragma unroll
    for (int kk = 0; kk < 16; ++kk) {
      float4 av = *(const float4*)&As[kk][ty * 4];
      float4 bv = *(const float4*)&Bs[kk][tx * 4];
      acc[0][0] += av.x * bv.x; acc[0][1] += av.x * bv.y; acc[0][2] += av.x * bv.z; acc[0][3] += av.x * bv.w;
      acc[1][0] += av.y * bv.x; acc[1][1] += av.y * bv.y; acc[1][2] += av.y * bv.z; acc[1][3] += av.y * bv.w;
      acc[2][0] += av.z * bv.x; acc[2][1] += av.z * bv.y; acc[2][2] += av.z * bv.z; acc[2][3] += av.z * bv.w;
      acc[3][0] += av.w * bv.x; acc[3][1] += av.w * bv.y; acc[3][2] += av.w * bv.z; acc[3][3] += av.w * bv.w;
    }
  }
  float4 bb = *(const float4*)&bias[col0 + tx * 4];
#pragma unroll
  for (int i = 0; i < 4; i++) {
    int gr = row0 + ty * 4 + i;
    int b2 = gr / Mb, m2 = gr - b2 * Mb;
    float4 o;
    o.x = acc[i][0] + bb.x; o.y = acc[i][1] + bb.y; o.z = acc[i][2] + bb.z; o.w = acc[i][3] + bb.w;
    if (relu) { o.x = fmaxf(o.x, 0.f); o.y = fmaxf(o.y, 0.f); o.z = fmaxf(o.z, 0.f); o.w = fmaxf(o.w, 0.f); }
    *(float4*)(C + (long)b2 * cBatchStride + (long)m2 * cRowStride + col0 + tx * 4) = o;
  }
}

// ---------------- note-segment scan: parallel runs-scan ----------------
__global__ __launch_bounds__(256) void seg_scan_kernel(const int* __restrict__ seq,
                                int* __restrict__ nstart, int* __restrict__ nlen) {
  __shared__ unsigned char v[P_];
  __shared__ int sc[2][256];
  int b = blockIdx.x, tid = threadIdx.x;
  for (int i = tid; i < P_; i += 256) {
    int s = seq[(long)b * P_ + i];
    v[i] = (s > 1 && i != P_ - 1) ? 1 : 0;   // last position never included
  }
  for (int n = tid; n < N_; n += 256) { nstart[b * N_ + n] = 0; nlen[b * N_ + n] = 0; }
  __syncthreads();
  int base = tid << 4;
  int c = 0;
#pragma unroll
  for (int i = 0; i < 16; i++) {
    int p = base + i;
    int val = v[p];
    int prev = p ? v[p - 1] : 0;
    c += val & (prev ^ 1);
  }
  sc[0][tid] = c;
  __syncthreads();
  int cur = 0;
  for (int d = 1; d < 256; d <<= 1) {
    int x = sc[cur][tid];
    if (tid >= d) x += sc[cur][tid - d];
    sc[cur ^ 1][tid] = x;
    cur ^= 1;
    __syncthreads();
  }
  int sg = tid ? sc[cur][tid - 1] : 0;   // exclusive prefix = first seg id in my chunk
  for (int i = 0; i < 16; i++) {
    int p = base + i;
    int val = v[p];
    int prev = p ? v[p - 1] : 0;
    if (val && !prev) {
      if (sg < N_) {
        int len = 0, q = p;
        while (q < P_ && v[q]) { len++; q++; }
        nstart[b * N_ + sg] = p;
        nlen[b * N_ + sg] = len;
      }
      sg++;
    }
  }
}

// ---------------- segment mean + enc (bf16, stride 272) ----------------
__global__ __launch_bounds__(256) void agg_enc_kernel(
    const float* __restrict__ X2c, const int* __restrict__ nstart, const int* __restrict__ nlen,
    const float* __restrict__ dur, u16* __restrict__ enc, int b0) {
  int n = blockIdx.x, gb = blockIdx.y;
  int b = b0 + gb;
  int d = threadIdx.x;
  int len = nlen[b * N_ + n], st = nstart[b * N_ + n];
  float acc = 0.f;
  for (int i = 0; i < len; i++) acc += X2c[((long)gb * PP + st + 1 + i) * CIN1P + d];
  float m = (len > 0) ? acc / (float)len : 0.f;
  long e = ((long)b * N_ + n) * 272;
  enc[e + d] = f2bf(m);
  if (d == 0) {
    float dd = dur[b * N_ + n];
    enc[e + 256] = f2bf(dd);
    enc[e + 257] = f2bf(1.f / (dd + 1.f));
  }
  if (d >= 2 && d < 16) enc[e + 256 + d] = 0;  // zero tail 258..271
}

// ---------------- LSTM recurrence v3: explicit named register weights ----------------
// 64 WGs (chain = dir*32+b), 512 threads; thread owns rows j=tid (units 0..127 x gates)
// and j=tid+512 (units 128..255). Z columns are PRE-PERMUTED (col j = logical row
// R(j)) so z loads are coalesced. k<192 weights in 48 NAMED uint4 (no arrays ->
// no scratch); k in [192,256) in 128KB LDS with lane-linear quads.
#define REC_LDS_BYTES (131072 + 4096 + 1024)
__global__ __launch_bounds__(512, 2) void lstm_rec2_kernel(
    const float* __restrict__ Z,      // [2][32][TCH][1024] fp32, permuted cols
    const uint4* __restrict__ Wv,     // [2][2][24][512] fp16 quads (k<192)
    const uint4* __restrict__ Ws,     // [2][2][8][512] fp16 quads (k>=192)
    float* __restrict__ state,        // [64][2][256]
    u16* __restrict__ Y, int yRowsPerB, int yPad, int r) {
  extern __shared__ char smem[];
  uint4* WL = (uint4*)smem;                              // 8192 quads
  float* zb = (float*)(smem + 131072);                   // 1024 f32
  u16*   hb = (u16*)(smem + 131072 + 4096);              // 256 fp16
  const uint4* hb4 = (const uint4*)hb;                   // 32 quads

  int chain = blockIdx.x;
  int d = chain >> 5, b = chain & 31;
  int tid = threadIdx.x;
  const float* Zb = Z + (long)(d * 32 + b) * (TCH * 1024);

  // stage LDS weights (linear copy; layout pre-baked by repack)
  for (int iq = 0; iq < 16; ++iq) {
    int q = iq * 512 + tid;
    WL[q] = Ws[(long)d * 8192 + q];
  }
  // load register weights into NAMED variables (48 x uint4 = 192 VGPRs)
  const uint4* WvD = Wv + (long)d * 2 * 24 * 512;
#define DECLW(i) uint4 wA##i, wB##i;
  REP24(DECLW)
#undef DECLW
#define LOADW(i) wA##i = WvD[(i) * 512 + tid]; wB##i = WvD[(24 + (i)) * 512 + tid];
  REP24(LOADW)
#undef LOADW

  float h_reg = 0.f, c_reg = 0.f;
  if (tid < 256) {
    if (r > 0) {
      h_reg = state[(chain * 2 + 0) * 256 + tid];
      c_reg = state[(chain * 2 + 1) * 256 + tid];
    }
    hb[tid] = f2h_bits(h_reg);
  }
  __syncthreads();

  int t0 = (d == 0) ? r * TCH : (NTCH - 1 - r) * TCH;
  int tcf = d ? (TCH - 1) : 0;
  float preA = Zb[(long)tcf * 1024 + tid];
  float preB = Zb[(long)tcf * 1024 + 512 + tid];

  for (int tt = 0; tt < TCH; ++tt) {
    float accA = preA, accB = preB;
    if (tt + 1 < TCH) {                       // prefetch next step's z (coalesced)
      int tc2 = d ? (TCH - 2 - tt) : (tt + 1);
      preA = Zb[(long)tc2 * 1024 + tid];
      preB = Zb[(long)tc2 * 1024 + 512 + tid];
    }
#define MACW(i) { uint4 hq = hb4[i]; DOT4(accA, wA##i, hq); DOT4(accB, wB##i, hq); }
    REP24(MACW)
#undef MACW
#define MACL(i) { uint4 hq = hb4[24 + (i)]; \
                  uint4 qa = WL[(i) * 512 + tid]; \
                  uint4 qb = WL[4096 + (i) * 512 + tid]; \
                  DOT4(accA, qa, hq); DOT4(accB, qb, hq); }
    REP8(MACL)
#undef MACL
    zb[tid] = accA;
    zb[tid + 512] = accB;
    __syncthreads();
    int tcur = d ? (TCH - 1 - tt) : tt;
    if (tid < 256) {
      float4 z4 = *(const float4*)&zb[tid * 4];   // (i,f,g,o) of unit tid
      float ig = sigmoidf_(z4.x), fg = sigmoidf_(z4.y);
      float gg = tanhf_(z4.z), og = sigmoidf_(z4.w);
      c_reg = fg * c_reg + ig * gg;
      float h = og * tanhf_(c_reg);
      h_reg = h;
      hb[tid] = f2h_bits(h);
      Y[((long)b * yRowsPerB + t0 + tcur + yPad) * 512 + d * 256 + tid] = f2bf(h);
    }
    __syncthreads();
  }
  if (r != NTCH - 1 && tid < 256) {
    state[(chain * 2 + 0) * 256 + tid] = h_reg;
    state[(chain * 2 + 1) * 256 + tid] = c_reg;
  }
}

// ---------------- final conv (Cout=1): wave per row ----------------
__global__ __launch_bounds__(256) void conv4_kernel(
    const float* __restrict__ C3p, const float* __restrict__ w,
    const float* __restrict__ b2, float* __restrict__ out) {
  int row = blockIdx.x * 4 + (threadIdx.x >> 6);
  int lane = threadIdx.x & 63;
  int b = row >> 10, t = row & (N_ - 1);
  const float* a = C3p + ((long)b * NP + t) * 256;
  float acc = 0.f;
  for (int k = lane; k < 768; k += 64) acc += a[k] * w[k];
  for (int off = 32; off; off >>= 1) acc += __shfl_down(acc, off, 64);
  if (lane == 0) out[row] = acc + b2[0];
}

// ---------------- host launcher ----------------
extern "C" void kernel_launch(void* const* d_in, const int* in_sizes, int n_in,
                              void* d_out, int out_size, void* d_ws, size_t ws_size,
                              hipStream_t stream) {
  const float* dur     = (const float*)d_in[0];
  const int*   seq     = (const int*)d_in[1];
  const int*   order   = (const int*)d_in[2];
  const float* emb     = (const float*)d_in[3];
  const float* pos_emb = (const float*)d_in[4];
  const float* mix_w1  = (const float*)d_in[5];
  const float* mix_b1  = (const float*)d_in[6];
  const float* mix_w2  = (const float*)d_in[7];
  const float* mix_b2  = (const float*)d_in[8];
  const float* wih0    = (const float*)d_in[9];
  const float* whh0    = (const float*)d_in[10];
  const float* bih0    = (const float*)d_in[11];
  const float* bhh0    = (const float*)d_in[12];
  const float* wih1    = (const float*)d_in[13];
  const float* whh1    = (const float*)d_in[14];
  const float* bih1    = (const float*)d_in[15];
  const float* bhh1    = (const float*)d_in[16];
  const float* cnn_w1  = (const float*)d_in[17];
  const float* cnn_b1  = (const float*)d_in[18];
  const float* cnn_w2  = (const float*)d_in[19];
  const float* cnn_b2  = (const float*)d_in[20];
  float* out = (float*)d_out;
  float* ws = (float*)d_ws;

  // opt-in to 136 KB dynamic LDS for the rec kernel (config call; capture-safe)
  (void)hipFuncSetAttribute((const void*)lstm_rec2_kernel,
                            hipFuncAttributeMaxDynamicSharedMemorySize, REC_LDS_BYTES);

  // ---- workspace layout (float units, 16-aligned) ----
  const long X0C_E = (long)GB * PP * CIN1P;
  const long X1C_E = (long)GB * PP * 256;
  const long Z_E   = 2L * B_ * TCH * 1024;
  const long C3P_E = (long)B_ * NP * 256;
  long region = X0C_E + X1C_E;
  if (Z_E > region) region = Z_E;
  if (C3P_E > region) region = C3P_E;

  long off = 0;
  auto alloc = [&](long n) { long ret = off; off += (n + 15) & ~15L; return ret; };
  long o_region = alloc(region);
  long o_enc    = alloc(((long)B_ * N_ * 272 + 1) / 2);   // bf16
  long o_Y0     = alloc(((long)B_ * N_ * 512 + 1) / 2);   // bf16
  long o_Y1p    = alloc(((long)B_ * NP * 512 + 1) / 2);   // bf16
  long o_W1r    = alloc(3L * CIN1P * 256);
  long o_W2r    = alloc(3L * 256 * 256);
  long o_Wc1r   = alloc(3L * 512 * 256);
  long o_Wc2r   = alloc(768);
  long o_Wih0r  = alloc(2L * 272 * 1024);
  long o_Wih1r  = alloc(2L * 512 * 1024);
  long o_Wv0    = alloc(49152L * 4);   // uint4 quads (fp16), layer0
  long o_Ws0    = alloc(16384L * 4);
  long o_Wv1    = alloc(49152L * 4);   // layer1
  long o_Ws1    = alloc(16384L * 4);
  long o_bs0    = alloc(2048);
  long o_bs1    = alloc(2048);
  long o_state  = alloc(64L * 2 * 256);
  long o_nst    = alloc((long)B_ * N_);
  long o_nln    = alloc((long)B_ * N_);

  if ((size_t)(off * 4) > ws_size) {
    float v = -(1000.0f + (float)(ws_size >> 20));
    fill_sentinel_kernel<<<(out_size + 255) / 256, 256, 0, stream>>>(out, out_size, v);
    return;
  }

  float* X0c  = ws + o_region;
  float* X1c  = ws + o_region + X0C_E;
  float* Z    = ws + o_region;              // alias (after phase A)
  float* C3p  = ws + o_region;              // alias (after recs)
  u16*   enc  = (u16*)(ws + o_enc);
  u16*   Y0   = (u16*)(ws + o_Y0);
  u16*   Y1p  = (u16*)(ws + o_Y1p);
  float* W1r  = ws + o_W1r;
  float* W2r  = ws + o_W2r;
  float* Wc1r = ws + o_Wc1r;
  float* Wc2r = ws + o_Wc2r;
  float* Wih0r = ws + o_Wih0r;
  float* Wih1r = ws + o_Wih1r;
  uint4* Wv0  = (uint4*)(ws + o_Wv0);
  uint4* Ws0  = (uint4*)(ws + o_Ws0);
  uint4* Wv1  = (uint4*)(ws + o_Wv1);
  uint4* Ws1  = (uint4*)(ws + o_Ws1);
  float* bs0  = ws + o_bs0;
  float* bs1  = ws + o_bs1;
  float* state = ws + o_state;
  int* nstart = (int*)(ws + o_nst);
  int* nlen   = (int*)(ws + o_nln);

  // ---- repacks / setup ----
  zero_chunk_guards_kernel<<<GB, 256, 0, stream>>>(X0c, X1c);
  zero_y1p_guards_kernel<<<B_, 256, 0, stream>>>(Y1p);
  repack_conv_w_kernel<<<(int)((3L * CIN1P * 256 + 255) / 256), 256, 0, stream>>>(mix_w1, W1r, 266, CIN1P, 256);
  repack_conv_w_kernel<<<(int)((3L * 256 * 256 + 255) / 256), 256, 0, stream>>>(mix_w2, W2r, 256, 256, 256);
  repack_conv_w_kernel<<<(int)((3L * 512 * 256 + 255) / 256), 256, 0, stream>>>(cnn_w1, Wc1r, 512, 512, 256);
  repack_conv4_w_kernel<<<3, 256, 0, stream>>>(cnn_w2, Wc2r);
  for (int d = 0; d < 2; d++) {
    repack_dense_w_perm_kernel<<<(272 * 1024 + 255) / 256, 256, 0, stream>>>(
        wih0 + (long)d * 1024 * 258, Wih0r + (long)d * 272 * 1024, 258, 272);
    repack_dense_w_perm_kernel<<<(512 * 1024 + 255) / 256, 256, 0, stream>>>(
        wih1 + (long)d * 1024 * 512, Wih1r + (long)d * 512 * 1024, 512, 512);
  }
  repack_whh_reg_kernel<<<192, 256, 0, stream>>>(whh0, Wv0);
  repack_whh_lds_kernel<<<64, 256, 0, stream>>>(whh0, Ws0);
  repack_whh_reg_kernel<<<192, 256, 0, stream>>>(whh1, Wv1);
  repack_whh_lds_kernel<<<64, 256, 0, stream>>>(whh1, Ws1);
  bias_sum_perm_kernel<<<8, 256, 0, stream>>>(bih0, bhh0, bs0);
  bias_sum_perm_kernel<<<8, 256, 0, stream>>>(bih1, bhh1, bs1);
  seg_scan_kernel<<<B_, 256, 0, stream>>>(seq, nstart, nlen);

  // ---- phase A: embed -> conv1 -> conv2 -> aggregate (8-batch chunks) ----
  for (int ch = 0; ch < NCHK; ch++) {
    int b0 = ch * GB;
    long total = (long)GB * P_ * CIN1P;
    embed_chunk_kernel<<<(int)((total + 255) / 256), 256, 0, stream>>>(seq, order, emb, pos_emb, X0c, b0);
    gemm_rows_kernel<float><<<dim3(GB * P_ / 64, 4), 256, 0, stream>>>(
        X0c, W1r, mix_b1, X1c + 256,
        256, 3 * CIN1P, P_, (long)PP * CIN1P, CIN1P, (long)PP * 256, 256, 1);
    gemm_rows_kernel<float><<<dim3(GB * P_ / 64, 4), 256, 0, stream>>>(
        X1c, W2r, mix_b2, X0c + CIN1P,
        256, 768, P_, (long)PP * 256, 256, (long)PP * CIN1P, CIN1P, 0);
    agg_enc_kernel<<<dim3(N_, GB), 256, 0, stream>>>(X0c, nstart, nlen, dur, enc, b0);
  }

  // ---- LSTM layers (time-chunked Z, GEMM + CU-resident rec) ----
  const long ZD = (long)B_ * TCH * 1024;
  for (int layer = 0; layer < 2; layer++) {
    const u16*  Xl   = (layer == 0) ? enc : Y0;
    int         xstr = (layer == 0) ? 272 : 512;
    int         Kp   = (layer == 0) ? 272 : 512;
    const float* Wih = (layer == 0) ? Wih0r : Wih1r;
    long        WihD = (layer == 0) ? (long)272 * 1024 : (long)512 * 1024;
    const float* bsl = (layer == 0) ? bs0 : bs1;
    const uint4* Wv  = (layer == 0) ? Wv0 : Wv1;
    const uint4* Wsp = (layer == 0) ? Ws0 : Ws1;
    u16*        Yl   = (layer == 0) ? Y0 : Y1p;
    int         yRows = (layer == 0) ? N_ : NP;
    int         yPad  = (layer == 0) ? 0 : 1;
    for (int r = 0; r < NTCH; r++) {
      for (int d = 0; d < 2; d++) {
        int t0 = (d == 0) ? r * TCH : (NTCH - 1 - r) * TCH;
        gemm_rows_kernel<u16><<<dim3(B_ * TCH / 64, 16), 256, 0, stream>>>(
            Xl + (long)t0 * xstr, Wih + (long)d * WihD, bsl + d * 1024, Z + d * ZD,
            1024, Kp, TCH, (long)N_ * xstr, xstr, (long)TCH * 1024, 1024, 0);
      }
      lstm_rec2_kernel<<<64, 512, REC_LDS_BYTES, stream>>>(Z, Wv, Wsp, state, Yl, yRows, yPad, r);
    }
  }

  // ---- head: conv(relu) K=1536 exact, then 1-channel conv ----
  zero_c3p_guards_kernel<<<B_, 256, 0, stream>>>(C3p);
  gemm_rows_kernel<u16><<<dim3(B_ * N_ / 64, 4), 256, 0, stream>>>(
      Y1p, Wc1r, cnn_b1, C3p + 256,
      256, 1536, N_, (long)NP * 512, 512, (long)NP * 256, 256, 1);
  conv4_kernel<<<B_ * N_ / 4, 256, 0, stream>>>(C3p, Wc2r, cnn_b2, out);
}

// Round 5
// 6989.308 us; speedup vs baseline: 2.8324x; 1.0011x over previous
//
#include <hip/hip_runtime.h>
#include <math.h>

#define B_    32
#define P_    4096
#define N_    1024
#define POS_  10
#define PP    (P_ + 2)     // padded phoneme rows (guard top/bottom)
#define NP    (N_ + 2)     // padded note rows
#define GB    8            // batches per phase-A chunk
#define NCHK  (B_ / GB)    // 4 phase-A chunks
#define TCH   256          // LSTM time chunk
#define NTCH  (N_ / TCH)   // 4 time chunks
#define CIN1P 272          // conv1 padded input channels (266 real)

typedef unsigned short u16;
typedef _Float16 h2_t __attribute__((ext_vector_type(2)));

// ---------------- helpers ----------------
__device__ __forceinline__ float sigmoidf_(float x) { return 1.f / (1.f + __expf(-x)); }
__device__ __forceinline__ float tanhf_(float x) {
  float t = fminf(fmaxf(x, -30.f), 30.f);
  float e = __expf(2.f * t);
  return (e - 1.f) / (e + 1.f);
}
__device__ __forceinline__ float bf2f(u16 u) { return __uint_as_float(((unsigned)u) << 16); }
__device__ __forceinline__ u16 f2bf(float f) {
  unsigned u = __float_as_uint(f);
  unsigned r = u + 0x7FFFu + ((u >> 16) & 1u);
  return (u16)(r >> 16);
}
__device__ __forceinline__ float ldA(const float* p) { return *p; }
__device__ __forceinline__ float ldA(const u16* p) { return bf2f(*p); }
__device__ __forceinline__ u16 f2h_bits(float x) {
  _Float16 hh = (_Float16)x; u16 u; __builtin_memcpy(&u, &hh, 2); return u;
}
__device__ __forceinline__ unsigned pack2h(float lo, float hi) {
  return (unsigned)f2h_bits(lo) | ((unsigned)f2h_bits(hi) << 16);
}
__device__ __forceinline__ float dot2(unsigned w, unsigned h, float acc) {
  return __builtin_amdgcn_fdot2(__builtin_bit_cast(h2_t, w), __builtin_bit_cast(h2_t, h), acc, false);
}
#define DOT4(acc, wq, hq) \
  acc = dot2((wq).x, (hq).x, acc); acc = dot2((wq).y, (hq).y, acc); \
  acc = dot2((wq).z, (hq).z, acc); acc = dot2((wq).w, (hq).w, acc);

#define REP24(X) X(0)X(1)X(2)X(3)X(4)X(5)X(6)X(7)X(8)X(9)X(10)X(11)X(12)X(13)X(14)X(15)X(16)X(17)X(18)X(19)X(20)X(21)X(22)X(23)
#define REP8(X)  X(0)X(1)X(2)X(3)X(4)X(5)X(6)X(7)

// ---------------- diagnostics ----------------
__global__ void fill_sentinel_kernel(float* out, int n, float v) {
  int i = blockIdx.x * 256 + threadIdx.x;
  if (i < n) out[i] = v;
}

// ---------------- zero guards ----------------
__global__ void zero_chunk_guards_kernel(float* X0c, float* X1c) {
  int cb = blockIdx.x, t = threadIdx.x;
  for (int c = t; c < CIN1P; c += 256) {
    X0c[((long)cb * PP + 0) * CIN1P + c] = 0.f;
    X0c[((long)cb * PP + PP - 1) * CIN1P + c] = 0.f;
  }
  if (t < 256) {
    X1c[((long)cb * PP + 0) * 256 + t] = 0.f;
    X1c[((long)cb * PP + PP - 1) * 256 + t] = 0.f;
  }
}
__global__ void zero_y1p_guards_kernel(u16* Y1p) {
  int b = blockIdx.x, t = threadIdx.x;
  for (int c = t; c < 512; c += 256) {
    Y1p[((long)b * NP + 0) * 512 + c] = 0;
    Y1p[((long)b * NP + NP - 1) * 512 + c] = 0;
  }
}
__global__ void zero_c3p_guards_kernel(float* C3p) {
  int b = blockIdx.x, t = threadIdx.x;
  if (t < 256) {
    C3p[((long)b * NP + 0) * 256 + t] = 0.f;
    C3p[((long)b * NP + NP - 1) * 256 + t] = 0.f;
  }
}

// ---------------- embedding (chunked) ----------------
__global__ void embed_chunk_kernel(const int* __restrict__ seq, const int* __restrict__ order,
                                   const float* __restrict__ emb, const float* __restrict__ pos_emb,
                                   float* __restrict__ X0c, int b0) {
  long i = (long)blockIdx.x * 256 + threadIdx.x;
  const long total = (long)GB * P_ * CIN1P;
  if (i >= total) return;
  int c = (int)(i % CIN1P);
  long bp = i / CIN1P;
  int p = (int)(bp % P_);
  int cb = (int)(bp / P_);
  int b = b0 + cb;
  float v = 0.f;
  if (c < 256)      v = emb[(long)seq[(long)b * P_ + p] * 256 + c];
  else if (c < 266) v = pos_emb[(long)order[(long)b * P_ + p] * POS_ + (c - 256)];
  X0c[((long)cb * PP + p + 1) * CIN1P + c] = v;
}

// ---------------- weight repacks ----------------
__global__ void repack_conv_w_kernel(const float* __restrict__ w, float* __restrict__ dst,
                                     int CinReal, int CinPad, int Cout) {
  long i = (long)blockIdx.x * 256 + threadIdx.x;
  long total = 3L * CinPad * Cout;
  if (i >= total) return;
  int k = (int)(i / Cout), co = (int)(i - (long)k * Cout);
  int rr = k / CinPad, ci = k - rr * CinPad;
  dst[i] = (ci < CinReal) ? w[((long)co * CinReal + ci) * 3 + rr] : 0.f;
}
// dense w[co(1024)][k] -> dst[k][j] with PERMUTED column j: co = R(j) = (j&3)*256 + (j>>2)
__global__ void repack_dense_w_perm_kernel(const float* __restrict__ w, float* __restrict__ dst,
                                           int CinReal, int Kpad) {
  long i = (long)blockIdx.x * 256 + threadIdx.x;
  if (i >= (long)Kpad * 1024) return;
  int k = (int)(i >> 10), j = (int)(i & 1023);
  int co = (j & 3) * 256 + (j >> 2);
  dst[i] = (k < CinReal) ? w[(long)co * CinReal + k] : 0.f;
}
// Whh k<192 slice -> register-resident quads: Wv[((d*2+rb)*24+kq)*512 + j]
// row(j,rb): R = (j&3)*256 + (j>>2) + rb*128; quad q covers k = kq*8+2q, +1
__global__ void repack_whh_reg_kernel(const float* __restrict__ whh, uint4* __restrict__ Wv) {
  long i = (long)blockIdx.x * 256 + threadIdx.x;
  if (i >= 49152) return;
  int j = (int)(i & 511);
  int t = (int)(i >> 9);
  int kq = t % 24, rb = (t / 24) & 1, d = t / 48;
  int R = (j & 3) * 256 + (j >> 2) + rb * 128;
  const float* wr = whh + ((long)d * 1024 + R) * 256;
  uint4 o; unsigned* op = (unsigned*)&o;
#pragma unroll
  for (int q = 0; q < 4; q++) {
    int k = kq * 8 + 2 * q;
    op[q] = pack2h(wr[k], wr[k + 1]);
  }
  Wv[i] = o;
}
// Whh k in [192,256) -> LDS-resident, LINEAR-LANE layout:
// Ws[d*8192 + rb*4096 + i2*512 + j]; R = (j&3)*256 + (j>>2) + rb*128; quad i2 covers k=192+i2*8+2q
__global__ void repack_whh_lds_kernel(const float* __restrict__ whh, uint4* __restrict__ Ws) {
  long i = (long)blockIdx.x * 256 + threadIdx.x;
  if (i >= 16384) return;
  int d = (int)(i >> 13);
  int a = (int)(i & 8191);
  int rb = a >> 12;
  int rem = a & 4095;
  int i2 = rem >> 9, j = rem & 511;
  int R = (j & 3) * 256 + (j >> 2) + rb * 128;
  const float* wr = whh + ((long)d * 1024 + R) * 256;
  uint4 o; unsigned* op = (unsigned*)&o;
#pragma unroll
  for (int q = 0; q < 4; q++) {
    int k = 192 + i2 * 8 + 2 * q;
    op[q] = pack2h(wr[k], wr[k + 1]);
  }
  Ws[i] = o;
}
// permuted bias sum: dst[d*1024 + j] = a[d*1024 + R(j)] + b[d*1024 + R(j)]
__global__ void bias_sum_perm_kernel(const float* __restrict__ a, const float* __restrict__ b,
                                     float* __restrict__ dst) {
  int i = blockIdx.x * 256 + threadIdx.x;
  if (i >= 2048) return;
  int d = i >> 10, j = i & 1023;
  int R = (j & 3) * 256 + (j >> 2);
  dst[i] = a[d * 1024 + R] + b[d * 1024 + R];
}
__global__ void repack_conv4_w_kernel(const float* __restrict__ w, float* __restrict__ dst) {
  int i = blockIdx.x * 256 + threadIdx.x;
  if (i < 768) { int r = i >> 8, ci = i & 255; dst[i] = w[ci * 3 + r]; }
}

// ---------------- rows-GEMM: C = A_rows @ Bm[Kpad x N] + bias ----------------
// As is column-XOR-swizzled to kill the 4-way write bank conflict:
//   store  As[k][ar ^ (((k>>2)&3)<<3)]   (k = akq+q, (k>>2)&3 == tid&3 -> constant/thread)
//   load   As[kk][(ty*4) ^ (((kk>>2)&3)<<3)]  (contiguous float4, 16B aligned, broadcast)
template <typename AT>
__global__ __launch_bounds__(256) void gemm_rows_kernel(
    const AT* __restrict__ A, const float* __restrict__ Bm,
    const float* __restrict__ bias, float* __restrict__ C,
    int N, int Kpad, int Mb,
    long aBatchStride, int aRowStride,
    long cBatchStride, int cRowStride,
    int relu) {
  __shared__ float As[16][64];   // [k][row^swz]
  __shared__ float Bs[16][64];   // [k][col]
  int tid = threadIdx.x;
  int row0 = blockIdx.x * 64;
  int col0 = blockIdx.y * 64;
  int tx = tid & 15, ty = tid >> 4;
  int ar = tid >> 2, akq = (tid & 3) * 4;
  int swzA = (tid & 3) << 3;            // == ((k>>2)&3)<<3 for k = akq+q
  int arS = ar ^ swzA;
  int grow = row0 + ar;
  int b_ = grow / Mb, m_ = grow - b_ * Mb;
  const AT* arow = A + (long)b_ * aBatchStride + (long)m_ * aRowStride;
  int kb = tid >> 4, nq = (tid & 15) * 4;
  const float* bptr = Bm + (long)kb * N + col0 + nq;

  float acc[4][4];
#pragma unroll
  for (int i = 0; i < 4; i++)
#pragma unroll
    for (int j = 0; j < 4; j++) acc[i][j] = 0.f;

  for (int k0 = 0; k0 < Kpad; k0 += 16) {
    float a0 = ldA(arow + k0 + akq + 0);
    float a1 = ldA(arow + k0 + akq + 1);
    float a2 = ldA(arow + k0 + akq + 2);
    float a3 = ldA(arow + k0 + akq + 3);
    float4 b4 = *(const float4*)(bptr + (long)k0 * N);
    __syncthreads();
    As[akq + 0][arS] = a0;
    As[akq + 1][arS] = a1;
    As[akq + 2][arS] = a2;
    As[akq + 3][arS] = a3;
    *(float4*)&Bs[kb][nq] = b4;
    __syncthreads();
#pragma unroll
    for (int kk = 0; kk < 16; ++kk) {
      float4 av = *(const float4*)&As[kk][(ty * 4) ^ (((kk >> 2) & 3) << 3)];
      float4 bv = *(const float4*)&Bs[kk][tx * 4];
      acc[0][0] += av.x * bv.x; acc[0][1] += av.x * bv.y; acc[0][2] += av.x * bv.z; acc[0][3] += av.x * bv.w;
      acc[1][0] += av.y * bv.x; acc[1][1] += av.y * bv.y; acc[1][2] += av.y * bv.z; acc[1][3] += av.y * bv.w;
      acc[2][0] += av.z * bv.x; acc[2][1] += av.z * bv.y; acc[2][2] += av.z * bv.z; acc[2][3] += av.z * bv.w;
      acc[3][0] += av.w * bv.x; acc[3][1] += av.w * bv.y; acc[3][2] += av.w * bv.z; acc[3][3] += av.w * bv.w;
    }
  }
  float4 bb = *(const float4*)&bias[col0 + tx * 4];
#pragma unroll
  for (int i = 0; i < 4; i++) {
    int gr = row0 + ty * 4 + i;
    int b2 = gr / Mb, m2 = gr - b2 * Mb;
    float4 o;
    o.x = acc[i][0] + bb.x; o.y = acc[i][1] + bb.y; o.z = acc[i][2] + bb.z; o.w = acc[i][3] + bb.w;
    if (relu) { o.x = fmaxf(o.x, 0.f); o.y = fmaxf(o.y, 0.f); o.z = fmaxf(o.z, 0.f); o.w = fmaxf(o.w, 0.f); }
    *(float4*)(C + (long)b2 * cBatchStride + (long)m2 * cRowStride + col0 + tx * 4) = o;
  }
}

// ---------------- note-segment scan: parallel runs-scan ----------------
__global__ __launch_bounds__(256) void seg_scan_kernel(const int* __restrict__ seq,
                                int* __restrict__ nstart, int* __restrict__ nlen) {
  __shared__ unsigned char v[P_];
  __shared__ int sc[2][256];
  int b = blockIdx.x, tid = threadIdx.x;
  for (int i = tid; i < P_; i += 256) {
    int s = seq[(long)b * P_ + i];
    v[i] = (s > 1 && i != P_ - 1) ? 1 : 0;   // last position never included
  }
  for (int n = tid; n < N_; n += 256) { nstart[b * N_ + n] = 0; nlen[b * N_ + n] = 0; }
  __syncthreads();
  int base = tid << 4;
  int c = 0;
#pragma unroll
  for (int i = 0; i < 16; i++) {
    int p = base + i;
    int val = v[p];
    int prev = p ? v[p - 1] : 0;
    c += val & (prev ^ 1);
  }
  sc[0][tid] = c;
  __syncthreads();
  int cur = 0;
  for (int d = 1; d < 256; d <<= 1) {
    int x = sc[cur][tid];
    if (tid >= d) x += sc[cur][tid - d];
    sc[cur ^ 1][tid] = x;
    cur ^= 1;
    __syncthreads();
  }
  int sg = tid ? sc[cur][tid - 1] : 0;   // exclusive prefix = first seg id in my chunk
  for (int i = 0; i < 16; i++) {
    int p = base + i;
    int val = v[p];
    int prev = p ? v[p - 1] : 0;
    if (val && !prev) {
      if (sg < N_) {
        int len = 0, q = p;
        while (q < P_ && v[q]) { len++; q++; }
        nstart[b * N_ + sg] = p;
        nlen[b * N_ + sg] = len;
      }
      sg++;
    }
  }
}

// ---------------- segment mean + enc (bf16, stride 272) ----------------
__global__ __launch_bounds__(256) void agg_enc_kernel(
    const float* __restrict__ X2c, const int* __restrict__ nstart, const int* __restrict__ nlen,
    const float* __restrict__ dur, u16* __restrict__ enc, int b0) {
  int n = blockIdx.x, gb = blockIdx.y;
  int b = b0 + gb;
  int d = threadIdx.x;
  int len = nlen[b * N_ + n], st = nstart[b * N_ + n];
  float acc = 0.f;
  for (int i = 0; i < len; i++) acc += X2c[((long)gb * PP + st + 1 + i) * CIN1P + d];
  float m = (len > 0) ? acc / (float)len : 0.f;
  long e = ((long)b * N_ + n) * 272;
  enc[e + d] = f2bf(m);
  if (d == 0) {
    float dd = dur[b * N_ + n];
    enc[e + 256] = f2bf(dd);
    enc[e + 257] = f2bf(1.f / (dd + 1.f));
  }
  if (d >= 2 && d < 16) enc[e + 256 + d] = 0;  // zero tail 258..271
}

// ---------------- LSTM recurrence v4: pinned 2 waves/EU => true register residency ----
// 64 WGs (chain = dir*32+b), 512 threads; thread owns rows j=tid and j=tid+512.
// Z columns PRE-PERMUTED (col j = logical row R(j)) -> coalesced z loads.
// k<192 weights in 48 NAMED uint4 (192 VGPRs); k in [192,256) in 128KB LDS.
// amdgpu_waves_per_eu(2,2) pins the allocator at the 256-VGPR budget so the
// occupancy heuristic cannot spill the weight quads (round-4 failure mode).
#define REC_LDS_BYTES (131072 + 4096 + 1024)
__global__ __attribute__((amdgpu_waves_per_eu(2, 2))) __launch_bounds__(512)
void lstm_rec2_kernel(
    const float* __restrict__ Z,      // [2][32][TCH][1024] fp32, permuted cols
    const uint4* __restrict__ Wv,     // [2][2][24][512] fp16 quads (k<192)
    const uint4* __restrict__ Ws,     // [2][2][8][512] fp16 quads (k>=192)
    float* __restrict__ state,        // [64][2][256]
    u16* __restrict__ Y, int yRowsPerB, int yPad, int r) {
  extern __shared__ char smem[];
  uint4* WL = (uint4*)smem;                              // 8192 quads
  float* zb = (float*)(smem + 131072);                   // 1024 f32
  u16*   hb = (u16*)(smem + 131072 + 4096);              // 256 fp16
  const uint4* hb4 = (const uint4*)hb;                   // 32 quads

  int chain = blockIdx.x;
  int d = chain >> 5, b = chain & 31;
  int tid = threadIdx.x;
  const float* Zb = Z + (long)(d * 32 + b) * (TCH * 1024);

  // stage LDS weights (linear copy; layout pre-baked by repack)
  for (int iq = 0; iq < 16; ++iq) {
    int q = iq * 512 + tid;
    WL[q] = Ws[(long)d * 8192 + q];
  }
  // load register weights into NAMED variables (48 x uint4 = 192 VGPRs)
  const uint4* WvD = Wv + (long)d * 2 * 24 * 512;
#define DECLW(i) uint4 wA##i, wB##i;
  REP24(DECLW)
#undef DECLW
#define LOADW(i) wA##i = WvD[(i) * 512 + tid]; wB##i = WvD[(24 + (i)) * 512 + tid];
  REP24(LOADW)
#undef LOADW

  float h_reg = 0.f, c_reg = 0.f;
  if (tid < 256) {
    if (r > 0) {
      h_reg = state[(chain * 2 + 0) * 256 + tid];
      c_reg = state[(chain * 2 + 1) * 256 + tid];
    }
    hb[tid] = f2h_bits(h_reg);
  }
  __syncthreads();

  int t0 = (d == 0) ? r * TCH : (NTCH - 1 - r) * TCH;
  int tcf = d ? (TCH - 1) : 0;
  float preA = Zb[(long)tcf * 1024 + tid];
  float preB = Zb[(long)tcf * 1024 + 512 + tid];

  for (int tt = 0; tt < TCH; ++tt) {
    float accA = preA, accB = preB;
    if (tt + 1 < TCH) {                       // prefetch next step's z (coalesced)
      int tc2 = d ? (TCH - 2 - tt) : (tt + 1);
      preA = Zb[(long)tc2 * 1024 + tid];
      preB = Zb[(long)tc2 * 1024 + 512 + tid];
    }
#define MACW(i) { uint4 hq = hb4[i]; DOT4(accA, wA##i, hq); DOT4(accB, wB##i, hq); }
    REP24(MACW)
#undef MACW
#define MACL(i) { uint4 hq = hb4[24 + (i)]; \
                  uint4 qa = WL[(i) * 512 + tid]; \
                  uint4 qb = WL[4096 + (i) * 512 + tid]; \
                  DOT4(accA, qa, hq); DOT4(accB, qb, hq); }
    REP8(MACL)
#undef MACL
    zb[tid] = accA;
    zb[tid + 512] = accB;
    __syncthreads();
    int tcur = d ? (TCH - 1 - tt) : tt;
    if (tid < 256) {
      float4 z4 = *(const float4*)&zb[tid * 4];   // (i,f,g,o) of unit tid
      float ig = sigmoidf_(z4.x), fg = sigmoidf_(z4.y);
      float gg = tanhf_(z4.z), og = sigmoidf_(z4.w);
      c_reg = fg * c_reg + ig * gg;
      float h = og * tanhf_(c_reg);
      h_reg = h;
      hb[tid] = f2h_bits(h);
      Y[((long)b * yRowsPerB + t0 + tcur + yPad) * 512 + d * 256 + tid] = f2bf(h);
    }
    __syncthreads();
  }
  if (r != NTCH - 1 && tid < 256) {
    state[(chain * 2 + 0) * 256 + tid] = h_reg;
    state[(chain * 2 + 1) * 256 + tid] = c_reg;
  }
}

// ---------------- final conv (Cout=1): wave per row ----------------
__global__ __launch_bounds__(256) void conv4_kernel(
    const float* __restrict__ C3p, const float* __restrict__ w,
    const float* __restrict__ b2, float* __restrict__ out) {
  int row = blockIdx.x * 4 + (threadIdx.x >> 6);
  int lane = threadIdx.x & 63;
  int b = row >> 10, t = row & (N_ - 1);
  const float* a = C3p + ((long)b * NP + t) * 256;
  float acc = 0.f;
  for (int k = lane; k < 768; k += 64) acc += a[k] * w[k];
  for (int off = 32; off; off >>= 1) acc += __shfl_down(acc, off, 64);
  if (lane == 0) out[row] = acc + b2[0];
}

// ---------------- host launcher ----------------
extern "C" void kernel_launch(void* const* d_in, const int* in_sizes, int n_in,
                              void* d_out, int out_size, void* d_ws, size_t ws_size,
                              hipStream_t stream) {
  const float* dur     = (const float*)d_in[0];
  const int*   seq     = (const int*)d_in[1];
  const int*   order   = (const int*)d_in[2];
  const float* emb     = (const float*)d_in[3];
  const float* pos_emb = (const float*)d_in[4];
  const float* mix_w1  = (const float*)d_in[5];
  const float* mix_b1  = (const float*)d_in[6];
  const float* mix_w2  = (const float*)d_in[7];
  const float* mix_b2  = (const float*)d_in[8];
  const float* wih0    = (const float*)d_in[9];
  const float* whh0    = (const float*)d_in[10];
  const float* bih0    = (const float*)d_in[11];
  const float* bhh0    = (const float*)d_in[12];
  const float* wih1    = (const float*)d_in[13];
  const float* whh1    = (const float*)d_in[14];
  const float* bih1    = (const float*)d_in[15];
  const float* bhh1    = (const float*)d_in[16];
  const float* cnn_w1  = (const float*)d_in[17];
  const float* cnn_b1  = (const float*)d_in[18];
  const float* cnn_w2  = (const float*)d_in[19];
  const float* cnn_b2  = (const float*)d_in[20];
  float* out = (float*)d_out;
  float* ws = (float*)d_ws;

  // opt-in to 136 KB dynamic LDS for the rec kernel (config call; capture-safe)
  (void)hipFuncSetAttribute((const void*)lstm_rec2_kernel,
                            hipFuncAttributeMaxDynamicSharedMemorySize, REC_LDS_BYTES);

  // ---- workspace layout (float units, 16-aligned) ----
  const long X0C_E = (long)GB * PP * CIN1P;
  const long X1C_E = (long)GB * PP * 256;
  const long Z_E   = 2L * B_ * TCH * 1024;
  const long C3P_E = (long)B_ * NP * 256;
  long region = X0C_E + X1C_E;
  if (Z_E > region) region = Z_E;
  if (C3P_E > region) region = C3P_E;

  long off = 0;
  auto alloc = [&](long n) { long ret = off; off += (n + 15) & ~15L; return ret; };
  long o_region = alloc(region);
  long o_enc    = alloc(((long)B_ * N_ * 272 + 1) / 2);   // bf16
  long o_Y0     = alloc(((long)B_ * N_ * 512 + 1) / 2);   // bf16
  long o_Y1p    = alloc(((long)B_ * NP * 512 + 1) / 2);   // bf16
  long o_W1r    = alloc(3L * CIN1P * 256);
  long o_W2r    = alloc(3L * 256 * 256);
  long o_Wc1r   = alloc(3L * 512 * 256);
  long o_Wc2r   = alloc(768);
  long o_Wih0r  = alloc(2L * 272 * 1024);
  long o_Wih1r  = alloc(2L * 512 * 1024);
  long o_Wv0    = alloc(49152L * 4);   // uint4 quads (fp16), layer0
  long o_Ws0    = alloc(16384L * 4);
  long o_Wv1    = alloc(49152L * 4);   // layer1
  long o_Ws1    = alloc(16384L * 4);
  long o_bs0    = alloc(2048);
  long o_bs1    = alloc(2048);
  long o_state  = alloc(64L * 2 * 256);
  long o_nst    = alloc((long)B_ * N_);
  long o_nln    = alloc((long)B_ * N_);

  if ((size_t)(off * 4) > ws_size) {
    float v = -(1000.0f + (float)(ws_size >> 20));
    fill_sentinel_kernel<<<(out_size + 255) / 256, 256, 0, stream>>>(out, out_size, v);
    return;
  }

  float* X0c  = ws + o_region;
  float* X1c  = ws + o_region + X0C_E;
  float* Z    = ws + o_region;              // alias (after phase A)
  float* C3p  = ws + o_region;              // alias (after recs)
  u16*   enc  = (u16*)(ws + o_enc);
  u16*   Y0   = (u16*)(ws + o_Y0);
  u16*   Y1p  = (u16*)(ws + o_Y1p);
  float* W1r  = ws + o_W1r;
  float* W2r  = ws + o_W2r;
  float* Wc1r = ws + o_Wc1r;
  float* Wc2r = ws + o_Wc2r;
  float* Wih0r = ws + o_Wih0r;
  float* Wih1r = ws + o_Wih1r;
  uint4* Wv0  = (uint4*)(ws + o_Wv0);
  uint4* Ws0  = (uint4*)(ws + o_Ws0);
  uint4* Wv1  = (uint4*)(ws + o_Wv1);
  uint4* Ws1  = (uint4*)(ws + o_Ws1);
  float* bs0  = ws + o_bs0;
  float* bs1  = ws + o_bs1;
  float* state = ws + o_state;
  int* nstart = (int*)(ws + o_nst);
  int* nlen   = (int*)(ws + o_nln);

  // ---- repacks / setup ----
  zero_chunk_guards_kernel<<<GB, 256, 0, stream>>>(X0c, X1c);
  zero_y1p_guards_kernel<<<B_, 256, 0, stream>>>(Y1p);
  repack_conv_w_kernel<<<(int)((3L * CIN1P * 256 + 255) / 256), 256, 0, stream>>>(mix_w1, W1r, 266, CIN1P, 256);
  repack_conv_w_kernel<<<(int)((3L * 256 * 256 + 255) / 256), 256, 0, stream>>>(mix_w2, W2r, 256, 256, 256);
  repack_conv_w_kernel<<<(int)((3L * 512 * 256 + 255) / 256), 256, 0, stream>>>(cnn_w1, Wc1r, 512, 512, 256);
  repack_conv4_w_kernel<<<3, 256, 0, stream>>>(cnn_w2, Wc2r);
  for (int d = 0; d < 2; d++) {
    repack_dense_w_perm_kernel<<<(272 * 1024 + 255) / 256, 256, 0, stream>>>(
        wih0 + (long)d * 1024 * 258, Wih0r + (long)d * 272 * 1024, 258, 272);
    repack_dense_w_perm_kernel<<<(512 * 1024 + 255) / 256, 256, 0, stream>>>(
        wih1 + (long)d * 1024 * 512, Wih1r + (long)d * 512 * 1024, 512, 512);
  }
  repack_whh_reg_kernel<<<192, 256, 0, stream>>>(whh0, Wv0);
  repack_whh_lds_kernel<<<64, 256, 0, stream>>>(whh0, Ws0);
  repack_whh_reg_kernel<<<192, 256, 0, stream>>>(whh1, Wv1);
  repack_whh_lds_kernel<<<64, 256, 0, stream>>>(whh1, Ws1);
  bias_sum_perm_kernel<<<8, 256, 0, stream>>>(bih0, bhh0, bs0);
  bias_sum_perm_kernel<<<8, 256, 0, stream>>>(bih1, bhh1, bs1);
  seg_scan_kernel<<<B_, 256, 0, stream>>>(seq, nstart, nlen);

  // ---- phase A: embed -> conv1 -> conv2 -> aggregate (8-batch chunks) ----
  for (int ch = 0; ch < NCHK; ch++) {
    int b0 = ch * GB;
    long total = (long)GB * P_ * CIN1P;
    embed_chunk_kernel<<<(int)((total + 255) / 256), 256, 0, stream>>>(seq, order, emb, pos_emb, X0c, b0);
    gemm_rows_kernel<float><<<dim3(GB * P_ / 64, 4), 256, 0, stream>>>(
        X0c, W1r, mix_b1, X1c + 256,
        256, 3 * CIN1P, P_, (long)PP * CIN1P, CIN1P, (long)PP * 256, 256, 1);
    gemm_rows_kernel<float><<<dim3(GB * P_ / 64, 4), 256, 0, stream>>>(
        X1c, W2r, mix_b2, X0c + CIN1P,
        256, 768, P_, (long)PP * 256, 256, (long)PP * CIN1P, CIN1P, 0);
    agg_enc_kernel<<<dim3(N_, GB), 256, 0, stream>>>(X0c, nstart, nlen, dur, enc, b0);
  }

  // ---- LSTM layers (time-chunked Z, GEMM + CU-resident rec) ----
  const long ZD = (long)B_ * TCH * 1024;
  for (int layer = 0; layer < 2; layer++) {
    const u16*  Xl   = (layer == 0) ? enc : Y0;
    int         xstr = (layer == 0) ? 272 : 512;
    int         Kp   = (layer == 0) ? 272 : 512;
    const float* Wih = (layer == 0) ? Wih0r : Wih1r;
    long        WihD = (layer == 0) ? (long)272 * 1024 : (long)512 * 1024;
    const float* bsl = (layer == 0) ? bs0 : bs1;
    const uint4* Wv  = (layer == 0) ? Wv0 : Wv1;
    const uint4* Wsp = (layer == 0) ? Ws0 : Ws1;
    u16*        Yl   = (layer == 0) ? Y0 : Y1p;
    int         yRows = (layer == 0) ? N_ : NP;
    int         yPad  = (layer == 0) ? 0 : 1;
    for (int r = 0; r < NTCH; r++) {
      for (int d = 0; d < 2; d++) {
        int t0 = (d == 0) ? r * TCH : (NTCH - 1 - r) * TCH;
        gemm_rows_kernel<u16><<<dim3(B_ * TCH / 64, 16), 256, 0, stream>>>(
            Xl + (long)t0 * xstr, Wih + (long)d * WihD, bsl + d * 1024, Z + d * ZD,
            1024, Kp, TCH, (long)N_ * xstr, xstr, (long)TCH * 1024, 1024, 0);
      }
      lstm_rec2_kernel<<<64, 512, REC_LDS_BYTES, stream>>>(Z, Wv, Wsp, state, Yl, yRows, yPad, r);
    }
  }

  // ---- head: conv(relu) K=1536 exact, then 1-channel conv ----
  zero_c3p_guards_kernel<<<B_, 256, 0, stream>>>(C3p);
  gemm_rows_kernel<u16><<<dim3(B_ * N_ / 64, 4), 256, 0, stream>>>(
      Y1p, Wc1r, cnn_b1, C3p + 256,
      256, 1536, N_, (long)NP * 512, 512, (long)NP * 256, 256, 1);
  conv4_kernel<<<B_ * N_ / 4, 256, 0, stream>>>(C3p, Wc2r, cnn_b2, out);
}